// Round 5
// baseline (200.579 us; speedup 1.0000x reference)
//
#include <hip/hip_runtime.h>
#include <hip/hip_bf16.h>

#define D_MODEL 1024
#define D_INNER 2048
#define D_STATE 16
#define DT_RANK 64
#define NB 2
#define LSEQ 1024
#define NROWS (NB * LSEQ)
#define XPN 96
#define NC 32
#define CL 32

typedef __attribute__((ext_vector_type(8))) short bf16x8;
typedef __attribute__((ext_vector_type(4))) float f32x4;

__device__ __forceinline__ unsigned short f2bf(float x) {
    __hip_bfloat16 h = __float2bfloat16(x);
    return *reinterpret_cast<unsigned short*>(&h);
}
__device__ __forceinline__ float bf2f(unsigned short u) {
    unsigned int v = ((unsigned int)u) << 16;
    float f;
    __builtin_memcpy(&f, &v, 4);
    return f;
}
__device__ __forceinline__ unsigned short f2h(float x) {
    _Float16 h = (_Float16)x;
    unsigned short u;
    __builtin_memcpy(&u, &h, 2);
    return u;
}
__device__ __forceinline__ float h2f(unsigned short u) {
    _Float16 h;
    __builtin_memcpy(&h, &u, 2);
    return (float)h;
}

// ---------------- LayerNorm -> bf16 out ----------------
__global__ __launch_bounds__(256) void ln_kernel(const float* __restrict__ x,
                                                 const float* __restrict__ w,
                                                 const float* __restrict__ bnorm,
                                                 unsigned short* __restrict__ outb) {
    int row = blockIdx.x;
    const float4* xr = (const float4*)(x + (size_t)row * D_MODEL);
    float4 v = xr[threadIdx.x];
    float s = v.x + v.y + v.z + v.w;
    float sq = v.x * v.x + v.y * v.y + v.z * v.z + v.w * v.w;
#pragma unroll
    for (int off = 32; off > 0; off >>= 1) {
        s += __shfl_down(s, off);
        sq += __shfl_down(sq, off);
    }
    __shared__ float ws[4], wq[4];
    __shared__ float smu, srstd;
    int wave = threadIdx.x >> 6;
    if ((threadIdx.x & 63) == 0) { ws[wave] = s; wq[wave] = sq; }
    __syncthreads();
    if (threadIdx.x == 0) {
        float ts = ws[0] + ws[1] + ws[2] + ws[3];
        float tq = wq[0] + wq[1] + wq[2] + wq[3];
        float mu = ts * (1.f / D_MODEL);
        float var = tq * (1.f / D_MODEL) - mu * mu;
        smu = mu;
        srstd = rsqrtf(var + 1e-5f);
    }
    __syncthreads();
    float mu = smu, rstd = srstd;
    float4 wv = ((const float4*)w)[threadIdx.x];
    float4 bv = ((const float4*)bnorm)[threadIdx.x];
    ushort4 pk;
    pk.x = f2bf((v.x - mu) * rstd * wv.x + bv.x);
    pk.y = f2bf((v.y - mu) * rstd * wv.y + bv.y);
    pk.z = f2bf((v.z - mu) * rstd * wv.z + bv.z);
    pk.w = f2bf((v.w - mu) * rstd * wv.w + bv.w);
    *(ushort4*)(outb + (size_t)row * D_MODEL + threadIdx.x * 4) = pk;
}

// ---------------- weight cast + transpose: W[K][Nreal] f32 -> Wt[Npad][K] bf16 ----------------
__global__ __launch_bounds__(256) void wcast_t(const float* __restrict__ W,
                                               unsigned short* __restrict__ Wt,
                                               int K, int Nreal, int Npad) {
    __shared__ float t[32][33];
    int tn = blockIdx.x * 32, tk = blockIdx.y * 32;
    for (int e = threadIdx.x; e < 1024; e += 256) {
        int r = e >> 5, c = e & 31;
        int n = tn + c;
        t[r][c] = (n < Nreal) ? W[(size_t)(tk + r) * Nreal + n] : 0.f;
    }
    __syncthreads();
    for (int e = threadIdx.x; e < 1024; e += 256) {
        int r = e >> 5, c = e & 31;
        Wt[(size_t)(tn + r) * K + tk + c] = f2bf(t[c][r]);
    }
}

// ---------------- bf16 MFMA GEMM: C = A[M][K] @ Bt[N][K]^T ----------------
// 128x128 tile, BK=32, 4 waves, global_load_lds, bijective XCD swizzle.
// EPI 0: f32 C (+split-K zoff). EPI 1: softplus(v+bias[col]) f32.
// EPI 2: in_proj xz-split: col<2048 -> C f32 [row][2048]; else -> C2 bf16 [row][2048].
// EPI 3: f16 partials into C2 (+split-K zoff).
template <int EPI>
__global__ __launch_bounds__(256) void gemm_bf16(const unsigned short* __restrict__ A,
                                                 const unsigned short* __restrict__ Bt,
                                                 const float* __restrict__ bias,
                                                 float* __restrict__ C,
                                                 void* __restrict__ C2,
                                                 int M, int K, int ldc, int Nreal) {
    __shared__ unsigned short As[128 * 32];
    __shared__ unsigned short Bs[128 * 32];
    int nwg = gridDim.x * gridDim.y;
    int orig = blockIdx.y * gridDim.x + blockIdx.x;
    int q = nwg >> 3, r = nwg & 7;
    int xcd = orig & 7, idx = orig >> 3;
    int newid = (xcd < r ? xcd * (q + 1) : r * (q + 1) + (xcd - r) * q) + idx;
    int bx = newid % gridDim.x, by = newid / gridDim.x;

    int tid = threadIdx.x;
    int lane = tid & 63;
    int wave = tid >> 6;
    int wr = (wave >> 1) * 64, wc = (wave & 1) * 64;
    int bm = by * 128, bn = bx * 128;
    int kchunk = K / gridDim.z;
    int kbeg = blockIdx.z * kchunk;

    f32x4 acc[4][4];
#pragma unroll
    for (int i = 0; i < 4; ++i)
#pragma unroll
        for (int j = 0; j < 4; ++j) acc[i][j] = (f32x4){0.f, 0.f, 0.f, 0.f};

    int r0 = tid >> 2;
    int c0 = (tid & 3) * 8;
    const unsigned short* a0 = A + (size_t)(bm + r0) * K + c0;
    const unsigned short* a1 = A + (size_t)(bm + 64 + r0) * K + c0;
    const unsigned short* b0 = Bt + (size_t)(bn + r0) * K + c0;
    const unsigned short* b1 = Bt + (size_t)(bn + 64 + r0) * K + c0;
    unsigned short* asw0 = As + (size_t)(tid & ~63) * 8;
    unsigned short* asw1 = As + 2048 + (size_t)(tid & ~63) * 8;
    unsigned short* bsw0 = Bs + (size_t)(tid & ~63) * 8;
    unsigned short* bsw1 = Bs + 2048 + (size_t)(tid & ~63) * 8;

    int ar = lane & 15;
    int ko = (lane >> 4) * 8;

    for (int k0 = kbeg; k0 < kbeg + kchunk; k0 += 32) {
        __syncthreads();
        __builtin_amdgcn_global_load_lds((const __attribute__((address_space(1))) void*)(a0 + k0),
                                         (__attribute__((address_space(3))) void*)asw0, 16, 0, 0);
        __builtin_amdgcn_global_load_lds((const __attribute__((address_space(1))) void*)(a1 + k0),
                                         (__attribute__((address_space(3))) void*)asw1, 16, 0, 0);
        __builtin_amdgcn_global_load_lds((const __attribute__((address_space(1))) void*)(b0 + k0),
                                         (__attribute__((address_space(3))) void*)bsw0, 16, 0, 0);
        __builtin_amdgcn_global_load_lds((const __attribute__((address_space(1))) void*)(b1 + k0),
                                         (__attribute__((address_space(3))) void*)bsw1, 16, 0, 0);
        __syncthreads();
        bf16x8 af[4], bfr[4];
#pragma unroll
        for (int i = 0; i < 4; ++i)
            af[i] = *(const bf16x8*)&As[(size_t)(wr + i * 16 + ar) * 32 + ko];
#pragma unroll
        for (int j = 0; j < 4; ++j)
            bfr[j] = *(const bf16x8*)&Bs[(size_t)(wc + j * 16 + ar) * 32 + ko];
#pragma unroll
        for (int i = 0; i < 4; ++i)
#pragma unroll
            for (int j = 0; j < 4; ++j)
                acc[i][j] = __builtin_amdgcn_mfma_f32_16x16x32_bf16(af[i], bfr[j], acc[i][j], 0, 0, 0);
    }

    int crow0 = bm + wr + (lane >> 4) * 4;
    int ccol0 = bn + wc + (lane & 15);
    size_t zoff = (size_t)blockIdx.z * (size_t)M * ldc;
#pragma unroll
    for (int i = 0; i < 4; ++i)
#pragma unroll
        for (int j = 0; j < 4; ++j) {
            int col = ccol0 + j * 16;
            if (EPI == 0) {
                if (col < Nreal) {
                    float* cp = C + zoff + (size_t)(crow0 + i * 16) * ldc + col;
#pragma unroll
                    for (int rr = 0; rr < 4; ++rr) cp[(size_t)rr * ldc] = acc[i][j][rr];
                }
            } else if (EPI == 1) {
                float bv = bias[col];
#pragma unroll
                for (int rr = 0; rr < 4; ++rr) {
                    float v = acc[i][j][rr] + bv;
                    v = (v > 20.f) ? v : log1pf(__expf(v));
                    C[(size_t)(crow0 + i * 16 + rr) * ldc + col] = v;
                }
            } else if (EPI == 2) {
                if (col < 2048) {
#pragma unroll
                    for (int rr = 0; rr < 4; ++rr)
                        C[(size_t)(crow0 + i * 16 + rr) * 2048 + col] = acc[i][j][rr];
                } else {
                    unsigned short* cz = (unsigned short*)C2;
#pragma unroll
                    for (int rr = 0; rr < 4; ++rr)
                        cz[(size_t)(crow0 + i * 16 + rr) * 2048 + (col - 2048)] = f2bf(acc[i][j][rr]);
                }
            } else {  // EPI == 3
                unsigned short* cp = (unsigned short*)C2 + zoff + (size_t)(crow0 + i * 16) * ldc + col;
#pragma unroll
                for (int rr = 0; rr < 4; ++rr) cp[(size_t)rr * ldc] = f2h(acc[i][j][rr]);
            }
        }
}

// ---------------- split-K reduce for xp (KS=16) + bf16 dt_r extract ----------------
__global__ __launch_bounds__(256) void reduce_xp(const float* __restrict__ part,
                                                 float* __restrict__ xp,
                                                 unsigned short* __restrict__ dtr) {
    int t = blockIdx.x * 256 + threadIdx.x;
    float s = 0.f;
#pragma unroll
    for (int k = 0; k < 16; ++k) s += part[(size_t)k * (NROWS * XPN) + t];
    xp[t] = s;
    int row = t / 96, col = t - row * 96;
    if (col < 64) dtr[(size_t)row * 64 + col] = f2bf(s);
}

// ---------------- split-K reduce for out (KS=4, f16 partials), 4 elems/thread ----------------
__global__ __launch_bounds__(256) void reduce_out(const unsigned short* __restrict__ part,
                                                  float* __restrict__ out) {
    int t = blockIdx.x * 256 + threadIdx.x;     // t indexes groups of 4
    const size_t stride = (size_t)NROWS * D_MODEL;
    ushort4 p0 = ((const ushort4*)part)[t];
    ushort4 p1 = ((const ushort4*)(part + stride))[t];
    ushort4 p2 = ((const ushort4*)(part + 2 * stride))[t];
    ushort4 p3 = ((const ushort4*)(part + 3 * stride))[t];
    float4 o;
    o.x = h2f(p0.x) + h2f(p1.x) + h2f(p2.x) + h2f(p3.x);
    o.y = h2f(p0.y) + h2f(p1.y) + h2f(p2.y) + h2f(p3.y);
    o.z = h2f(p0.z) + h2f(p1.z) + h2f(p2.z) + h2f(p3.z);
    o.w = h2f(p0.w) + h2f(p1.w) + h2f(p2.w) + h2f(p3.w);
    ((float4*)out)[t] = o;
}

// ---------------- causal depthwise conv (k=4) + SiLU -> bf16 only ----------------
__global__ __launch_bounds__(256) void conv_silu_kernel(const float* __restrict__ xx,
                                                        const float* __restrict__ cw,
                                                        const float* __restrict__ cb,
                                                        unsigned short* __restrict__ outb) {
    int gid = blockIdx.x * 256 + threadIdx.x;
    int d4 = (gid & 511) << 2;
    int bl = gid >> 9;
    int l = bl & (LSEQ - 1);
    const float* base = xx + (size_t)bl * D_INNER + d4;
    float4 zr = make_float4(0.f, 0.f, 0.f, 0.f);
    float4 x0 = *(const float4*)base;
    float4 x1 = (l >= 1) ? *(const float4*)(base - D_INNER) : zr;
    float4 x2 = (l >= 2) ? *(const float4*)(base - 2 * D_INNER) : zr;
    float4 x3 = (l >= 3) ? *(const float4*)(base - 3 * D_INNER) : zr;
    float4 bias = *(const float4*)(cb + d4);
    const float4* wv = (const float4*)(cw + (size_t)d4 * 4);
    float xs0[4] = {x0.x, x0.y, x0.z, x0.w};
    float xs1[4] = {x1.x, x1.y, x1.z, x1.w};
    float xs2[4] = {x2.x, x2.y, x2.z, x2.w};
    float xs3[4] = {x3.x, x3.y, x3.z, x3.w};
    float bs[4] = {bias.x, bias.y, bias.z, bias.w};
    ushort4 ob;
    unsigned short* obp = (unsigned short*)&ob;
#pragma unroll
    for (int e = 0; e < 4; ++e) {
        float4 we = wv[e];
        float acc = bs[e];
        acc = fmaf(we.w, xs0[e], acc);
        acc = fmaf(we.z, xs1[e], acc);
        acc = fmaf(we.y, xs2[e], acc);
        acc = fmaf(we.x, xs3[e], acc);
        obp[e] = f2bf(acc / (1.f + __expf(-acc)));
    }
    *(ushort4*)(outb + (size_t)bl * D_INNER + d4) = ob;
}

// ---------------- scan phase 1: per-chunk local scan (h0 = 0) ----------------
__global__ __launch_bounds__(256) void scan_local(const float* __restrict__ xp,
                                                  const float* __restrict__ delta,
                                                  const unsigned short* __restrict__ ub,
                                                  const float* __restrict__ A_log,
                                                  float* __restrict__ hst,
                                                  float* __restrict__ sdel) {
    int bc = blockIdx.x >> 3;
    int b = bc >> 5, c = bc & (NC - 1);
    int d = (blockIdx.x & 7) * 256 + threadIdx.x;
    int base_r = b * LSEQ + c * CL;
    __shared__ float Bsm[CL * 16];
    for (int e = threadIdx.x; e < CL * 16; e += 256) {
        int l = e >> 4, n = e & 15;
        Bsm[e] = xp[(size_t)(base_r + l) * XPN + DT_RANK + n];
    }
    __syncthreads();
    float Av[16];
    const float4* ap = (const float4*)(A_log + (size_t)d * 16);
#pragma unroll
    for (int qq = 0; qq < 4; ++qq) {
        float4 a = ap[qq];
        Av[4 * qq + 0] = -__expf(a.x); Av[4 * qq + 1] = -__expf(a.y);
        Av[4 * qq + 2] = -__expf(a.z); Av[4 * qq + 3] = -__expf(a.w);
    }
    float h[16] = {};
    float sd = 0.f;
    const float* dp = delta + (size_t)base_r * D_INNER + d;
    const unsigned short* up = ub + (size_t)base_r * D_INNER + d;
#pragma unroll 4
    for (int l = 0; l < CL; ++l) {
        float dv = dp[(size_t)l * D_INNER];
        float u = bf2f(up[(size_t)l * D_INNER]);
        float du = dv * u;
        sd += dv;
#pragma unroll
        for (int n = 0; n < 16; ++n) {
            float dA = __expf(dv * Av[n]);
            h[n] = fmaf(dA, h[n], du * Bsm[l * 16 + n]);
        }
    }
    size_t hi = ((size_t)(c * NB + b) * D_INNER + d) * 16;
#pragma unroll
    for (int qq = 0; qq < 4; ++qq) {
        float4 v = make_float4(h[4 * qq], h[4 * qq + 1], h[4 * qq + 2], h[4 * qq + 3]);
        *(float4*)(hst + hi + 4 * qq) = v;
    }
    sdel[(size_t)(c * NB + b) * D_INNER + d] = sd;
}

// ---------------- scan phase 2: cross-chunk combine ----------------
__global__ __launch_bounds__(256) void scan_combine(const float* __restrict__ A_log,
                                                    const float* __restrict__ sdel,
                                                    float* __restrict__ hst) {
    int t = blockIdx.x * 256 + threadIdx.x;
    int n = t & 15, d = (t >> 4) & (D_INNER - 1), b = t >> 15;
    float Avn = -__expf(A_log[(size_t)d * 16 + n]);
    float h = 0.f;
#pragma unroll 4
    for (int c = 0; c < NC; ++c) {
        size_t base = (size_t)(c * NB + b) * D_INNER + d;
        float* hp = hst + base * 16 + n;
        float S = sdel[base];
        float tmp = *hp;
        *hp = h;
        h = fmaf(__expf(Avn * S), h, tmp);
    }
}

// ---------------- scan phase 3: finalize, fuse silu(z) gate -> bf16 y ----------------
__global__ __launch_bounds__(256) void scan_final(const float* __restrict__ xp,
                                                  const float* __restrict__ dlt,
                                                  const unsigned short* __restrict__ ub,
                                                  const unsigned short* __restrict__ zb,
                                                  const float* __restrict__ hst,
                                                  const float* __restrict__ A_log,
                                                  const float* __restrict__ Dp,
                                                  unsigned short* __restrict__ yb) {
    int bc = blockIdx.x >> 3;
    int b = bc >> 5, c = bc & (NC - 1);
    int d = (blockIdx.x & 7) * 256 + threadIdx.x;
    int base_r = b * LSEQ + c * CL;
    __shared__ float Bsm[CL * 16], Csm[CL * 16];
    for (int e = threadIdx.x; e < CL * 16; e += 256) {
        int l = e >> 4, n = e & 15;
        Bsm[e] = xp[(size_t)(base_r + l) * XPN + DT_RANK + n];
        Csm[e] = xp[(size_t)(base_r + l) * XPN + DT_RANK + 16 + n];
    }
    __syncthreads();
    float Av[16];
    const float4* ap = (const float4*)(A_log + (size_t)d * 16);
#pragma unroll
    for (int qq = 0; qq < 4; ++qq) {
        float4 a = ap[qq];
        Av[4 * qq + 0] = -__expf(a.x); Av[4 * qq + 1] = -__expf(a.y);
        Av[4 * qq + 2] = -__expf(a.z); Av[4 * qq + 3] = -__expf(a.w);
    }
    float h[16];
    size_t hi = ((size_t)(c * NB + b) * D_INNER + d) * 16;
#pragma unroll
    for (int qq = 0; qq < 4; ++qq) {
        float4 v = *(const float4*)(hst + hi + 4 * qq);
        h[4 * qq] = v.x; h[4 * qq + 1] = v.y; h[4 * qq + 2] = v.z; h[4 * qq + 3] = v.w;
    }
    float Dv = Dp[d];
    const float* dyp = dlt + (size_t)base_r * D_INNER + d;
    const unsigned short* up = ub + (size_t)base_r * D_INNER + d;
    const unsigned short* zp = zb + (size_t)base_r * D_INNER + d;
#pragma unroll 4
    for (int l = 0; l < CL; ++l) {
        float dv = dyp[(size_t)l * D_INNER];
        float u = bf2f(up[(size_t)l * D_INNER]);
        float du = dv * u;
        float acc = 0.f;
#pragma unroll
        for (int n = 0; n < 16; ++n) {
            float dA = __expf(dv * Av[n]);
            h[n] = fmaf(dA, h[n], du * Bsm[l * 16 + n]);
            acc = fmaf(h[n], Csm[l * 16 + n], acc);
        }
        float yv = fmaf(u, Dv, acc);
        float zv = bf2f(zp[(size_t)l * D_INNER]);
        float sz = zv / (1.f + __expf(-zv));
        yb[(size_t)(base_r + l) * D_INNER + d] = f2bf(yv * sz);
    }
}

extern "C" void kernel_launch(void* const* d_in, const int* in_sizes, int n_in,
                              void* d_out, int out_size, void* d_ws, size_t ws_size,
                              hipStream_t stream) {
    const float* hidden = (const float*)d_in[0];
    const float* norm_w = (const float*)d_in[1];
    const float* norm_b = (const float*)d_in[2];
    const float* in_proj_w = (const float*)d_in[3];
    const float* conv_w = (const float*)d_in[4];
    const float* conv_b = (const float*)d_in[5];
    const float* x_proj_w = (const float*)d_in[6];
    const float* dt_proj_w = (const float*)d_in[7];
    const float* dt_proj_b = (const float*)d_in[8];
    const float* A_log = (const float*)d_in[9];
    const float* D_param = (const float*)d_in[10];
    const float* out_proj_w = (const float*)d_in[11];
    float* out = (float*)d_out;

    float* wsf = (float*)d_ws;
    // region 0: [0 .. 1,048,576) floats — time-shared
    unsigned short* hbufb = (unsigned short*)wsf;             // LN out bf16 [2048][1024]
    float* xpbuf = wsf;                                       // xp f32 [2048][96] (after in_proj)
    float* sdelbuf = wsf + 196608;                            // [64][2048]
    unsigned short* dtrb = (unsigned short*)(wsf + 327680);   // dt_r bf16 [2048][64]
    unsigned short* wDt = (unsigned short*)(wsf + 458752);    // dt_proj_w^T bf16 [2048][64]
    unsigned short* wOt = (unsigned short*)wsf;               // out_proj_w^T bf16 (after scan_final)
    float* xzx = wsf + 1048576;                               // x-half f32 [2048][2048]; later hst; later f16 out-partials
    unsigned short* xzz = (unsigned short*)(wsf + 5242880);   // z-half bf16 [2048][2048]
    unsigned short* xcb = (unsigned short*)(wsf + 7340032);   // conv-out bf16 [2048][2048]; later yb
    unsigned short* yb = xcb;
    float* dltbuf = wsf + 9437184;                            // delta f32 [2048][2048] — time-shared:
    unsigned short* wAt = (unsigned short*)dltbuf;            //   in_proj_w^T bf16 [4096][1024]
    float* xpart = dltbuf;                                    //   x_proj partials [16][2048][96]
    unsigned short* wXt = (unsigned short*)(dltbuf + 3145728);//   x_proj_w^T bf16 [128][2048]
    float* hst = xzx;                                         // h states [64][2048][16] (after conv)
    unsigned short* opart = (unsigned short*)xzx;             // f16 out partials [4][2048][1024] (after scan_final)

    // weight casts
    wcast_t<<<dim3(4096 / 32, 1024 / 32), 256, 0, stream>>>(in_proj_w, wAt, 1024, 4096, 4096);
    wcast_t<<<dim3(128 / 32, 2048 / 32), 256, 0, stream>>>(x_proj_w, wXt, 2048, 96, 128);

    // LayerNorm -> bf16
    ln_kernel<<<NROWS, 256, 0, stream>>>(hidden, norm_w, norm_b, hbufb);

    // xz = h @ in_proj_w : x-half f32 -> xzx, z-half bf16 -> xzz
    gemm_bf16<2><<<dim3(4096 / 128, NROWS / 128, 1), 256, 0, stream>>>(
        hbufb, wAt, nullptr, xzx, xzz, NROWS, 1024, 2048, 4096);

    // dt weight cast
    wcast_t<<<dim3(2048 / 32, 64 / 32), 256, 0, stream>>>(dt_proj_w, wDt, 64, 2048, 2048);

    // conv + silu -> bf16 u
    conv_silu_kernel<<<(NROWS * D_INNER) / 1024, 256, 0, stream>>>(xzx, conv_w, conv_b, xcb);

    // xp partials = u @ x_proj_w (split-K = 16)
    gemm_bf16<0><<<dim3(1, NROWS / 128, 16), 256, 0, stream>>>(
        xcb, wXt, nullptr, xpart, nullptr, NROWS, 2048, XPN, XPN);

    // reduce partials -> xp f32 + dt_r bf16
    reduce_xp<<<(NROWS * XPN) / 256, 256, 0, stream>>>(xpart, xpbuf, dtrb);

    // delta = softplus(dt_r @ dt_proj_w + b)
    gemm_bf16<1><<<dim3(D_INNER / 128, NROWS / 128, 1), 256, 0, stream>>>(
        dtrb, wDt, dt_proj_b, dltbuf, nullptr, NROWS, 64, D_INNER, D_INNER);

    // chunked selective scan + fused gate -> bf16 y
    scan_local<<<NB * NC * (D_INNER / 256), 256, 0, stream>>>(
        xpbuf, dltbuf, xcb, A_log, hst, sdelbuf);
    scan_combine<<<(NB * D_INNER * D_STATE) / 256, 256, 0, stream>>>(
        A_log, sdelbuf, hst);
    scan_final<<<NB * NC * (D_INNER / 256), 256, 0, stream>>>(
        xpbuf, dltbuf, xcb, xzz, hst, A_log, D_param, yb);

    // out_proj weight cast (region 0 dead after scan_final)
    wcast_t<<<dim3(1024 / 32, 2048 / 32), 256, 0, stream>>>(out_proj_w, wOt, 2048, 1024, 1024);

    // out partials = y @ out_proj_w (split-K = 4, f16 partials in dead xzx)
    gemm_bf16<3><<<dim3(1024 / 128, NROWS / 128, 4), 256, 0, stream>>>(
        yb, wOt, nullptr, nullptr, opart, NROWS, 2048, 1024, 1024);

    // reduce f16 partials -> d_out
    reduce_out<<<(NROWS * D_MODEL / 4) / 256, 256, 0, stream>>>(opart, out);
}

// Round 6
// 193.853 us; speedup vs baseline: 1.0347x; 1.0347x over previous
//
#include <hip/hip_runtime.h>
#include <hip/hip_bf16.h>

#define D_MODEL 1024
#define D_INNER 2048
#define D_STATE 16
#define DT_RANK 64
#define NB 2
#define LSEQ 1024
#define NROWS (NB * LSEQ)
#define XPN 96
#define NC 32
#define CL 32
#define DR_ROWS 8

typedef __attribute__((ext_vector_type(8))) short bf16x8;
typedef __attribute__((ext_vector_type(4))) float f32x4;

__device__ __forceinline__ unsigned short f2bf(float x) {
    __hip_bfloat16 h = __float2bfloat16(x);
    return *reinterpret_cast<unsigned short*>(&h);
}
__device__ __forceinline__ float bf2f(unsigned short u) {
    unsigned int v = ((unsigned int)u) << 16;
    float f;
    __builtin_memcpy(&f, &v, 4);
    return f;
}
__device__ __forceinline__ unsigned short f2h(float x) {
    _Float16 h = (_Float16)x;
    unsigned short u;
    __builtin_memcpy(&u, &h, 2);
    return u;
}
__device__ __forceinline__ float h2f(unsigned short u) {
    _Float16 h;
    __builtin_memcpy(&h, &u, 2);
    return (float)h;
}

// ---------------- LayerNorm -> bf16 out ----------------
__global__ __launch_bounds__(256) void ln_kernel(const float* __restrict__ x,
                                                 const float* __restrict__ w,
                                                 const float* __restrict__ bnorm,
                                                 unsigned short* __restrict__ outb) {
    int row = blockIdx.x;
    const float4* xr = (const float4*)(x + (size_t)row * D_MODEL);
    float4 v = xr[threadIdx.x];
    float s = v.x + v.y + v.z + v.w;
    float sq = v.x * v.x + v.y * v.y + v.z * v.z + v.w * v.w;
#pragma unroll
    for (int off = 32; off > 0; off >>= 1) {
        s += __shfl_down(s, off);
        sq += __shfl_down(sq, off);
    }
    __shared__ float ws[4], wq[4];
    __shared__ float smu, srstd;
    int wave = threadIdx.x >> 6;
    if ((threadIdx.x & 63) == 0) { ws[wave] = s; wq[wave] = sq; }
    __syncthreads();
    if (threadIdx.x == 0) {
        float ts = ws[0] + ws[1] + ws[2] + ws[3];
        float tq = wq[0] + wq[1] + wq[2] + wq[3];
        float mu = ts * (1.f / D_MODEL);
        float var = tq * (1.f / D_MODEL) - mu * mu;
        smu = mu;
        srstd = rsqrtf(var + 1e-5f);
    }
    __syncthreads();
    float mu = smu, rstd = srstd;
    float4 wv = ((const float4*)w)[threadIdx.x];
    float4 bv = ((const float4*)bnorm)[threadIdx.x];
    ushort4 pk;
    pk.x = f2bf((v.x - mu) * rstd * wv.x + bv.x);
    pk.y = f2bf((v.y - mu) * rstd * wv.y + bv.y);
    pk.z = f2bf((v.z - mu) * rstd * wv.z + bv.z);
    pk.w = f2bf((v.w - mu) * rstd * wv.w + bv.w);
    *(ushort4*)(outb + (size_t)row * D_MODEL + threadIdx.x * 4) = pk;
}

// ---------------- all 3 weight casts in ONE dispatch ----------------
// job0: in_proj [1024][4096] -> wAt[4096][1024]   (4096 blocks)
// job1: x_proj  [2048][96]   -> wXt[128][2048]    (256 blocks, zero-padded)
// job2: out_proj[2048][1024] -> wOt[1024][2048]   (2048 blocks)
__global__ __launch_bounds__(256) void wcast_all(const float* __restrict__ W0, unsigned short* __restrict__ D0,
                                                 const float* __restrict__ W1, unsigned short* __restrict__ D1,
                                                 const float* __restrict__ W2, unsigned short* __restrict__ D2) {
    int bid = blockIdx.x;
    const float* W;
    unsigned short* Dst;
    int K, Nreal, bx, by;
    if (bid < 4096) { W = W0; Dst = D0; K = 1024; Nreal = 4096; bx = bid & 127; by = bid >> 7; }
    else if (bid < 4352) { int j = bid - 4096; W = W1; Dst = D1; K = 2048; Nreal = 96; bx = j & 3; by = j >> 2; }
    else { int j = bid - 4352; W = W2; Dst = D2; K = 2048; Nreal = 1024; bx = j & 31; by = j >> 5; }
    __shared__ float t[32][33];
    int tn = bx * 32, tk = by * 32;
    for (int e = threadIdx.x; e < 1024; e += 256) {
        int r = e >> 5, c = e & 31;
        int n = tn + c;
        t[r][c] = (n < Nreal) ? W[(size_t)(tk + r) * Nreal + n] : 0.f;
    }
    __syncthreads();
    for (int e = threadIdx.x; e < 1024; e += 256) {
        int r = e >> 5, c = e & 31;
        Dst[(size_t)(tn + r) * K + tk + c] = f2bf(t[c][r]);
    }
}

// ---------------- bf16 MFMA GEMM: C = A[M][K] @ Bt[N][K]^T ----------------
// EPI 0: f32 C (+split-K zoff). EPI 2: xz-split, both halves bf16 (x->C, z->C2).
// EPI 3: f16 partials into C2 (+split-K zoff).
template <int EPI>
__global__ __launch_bounds__(256) void gemm_bf16(const unsigned short* __restrict__ A,
                                                 const unsigned short* __restrict__ Bt,
                                                 float* __restrict__ C,
                                                 void* __restrict__ C2,
                                                 int M, int K, int ldc, int Nreal) {
    __shared__ unsigned short As[128 * 32];
    __shared__ unsigned short Bs[128 * 32];
    int nwg = gridDim.x * gridDim.y;
    int orig = blockIdx.y * gridDim.x + blockIdx.x;
    int q = nwg >> 3, r = nwg & 7;
    int xcd = orig & 7, idx = orig >> 3;
    int newid = (xcd < r ? xcd * (q + 1) : r * (q + 1) + (xcd - r) * q) + idx;
    int bx = newid % gridDim.x, by = newid / gridDim.x;

    int tid = threadIdx.x;
    int lane = tid & 63;
    int wave = tid >> 6;
    int wr = (wave >> 1) * 64, wc = (wave & 1) * 64;
    int bm = by * 128, bn = bx * 128;
    int kchunk = K / gridDim.z;
    int kbeg = blockIdx.z * kchunk;

    f32x4 acc[4][4];
#pragma unroll
    for (int i = 0; i < 4; ++i)
#pragma unroll
        for (int j = 0; j < 4; ++j) acc[i][j] = (f32x4){0.f, 0.f, 0.f, 0.f};

    int r0 = tid >> 2;
    int c0 = (tid & 3) * 8;
    const unsigned short* a0 = A + (size_t)(bm + r0) * K + c0;
    const unsigned short* a1 = A + (size_t)(bm + 64 + r0) * K + c0;
    const unsigned short* b0 = Bt + (size_t)(bn + r0) * K + c0;
    const unsigned short* b1 = Bt + (size_t)(bn + 64 + r0) * K + c0;
    unsigned short* asw0 = As + (size_t)(tid & ~63) * 8;
    unsigned short* asw1 = As + 2048 + (size_t)(tid & ~63) * 8;
    unsigned short* bsw0 = Bs + (size_t)(tid & ~63) * 8;
    unsigned short* bsw1 = Bs + 2048 + (size_t)(tid & ~63) * 8;

    int ar = lane & 15;
    int ko = (lane >> 4) * 8;

    for (int k0 = kbeg; k0 < kbeg + kchunk; k0 += 32) {
        __syncthreads();
        __builtin_amdgcn_global_load_lds((const __attribute__((address_space(1))) void*)(a0 + k0),
                                         (__attribute__((address_space(3))) void*)asw0, 16, 0, 0);
        __builtin_amdgcn_global_load_lds((const __attribute__((address_space(1))) void*)(a1 + k0),
                                         (__attribute__((address_space(3))) void*)asw1, 16, 0, 0);
        __builtin_amdgcn_global_load_lds((const __attribute__((address_space(1))) void*)(b0 + k0),
                                         (__attribute__((address_space(3))) void*)bsw0, 16, 0, 0);
        __builtin_amdgcn_global_load_lds((const __attribute__((address_space(1))) void*)(b1 + k0),
                                         (__attribute__((address_space(3))) void*)bsw1, 16, 0, 0);
        __syncthreads();
        bf16x8 af[4], bfr[4];
#pragma unroll
        for (int i = 0; i < 4; ++i)
            af[i] = *(const bf16x8*)&As[(size_t)(wr + i * 16 + ar) * 32 + ko];
#pragma unroll
        for (int j = 0; j < 4; ++j)
            bfr[j] = *(const bf16x8*)&Bs[(size_t)(wc + j * 16 + ar) * 32 + ko];
#pragma unroll
        for (int i = 0; i < 4; ++i)
#pragma unroll
            for (int j = 0; j < 4; ++j)
                acc[i][j] = __builtin_amdgcn_mfma_f32_16x16x32_bf16(af[i], bfr[j], acc[i][j], 0, 0, 0);
    }

    int crow0 = bm + wr + (lane >> 4) * 4;
    int ccol0 = bn + wc + (lane & 15);
    size_t zoff = (size_t)blockIdx.z * (size_t)M * ldc;
#pragma unroll
    for (int i = 0; i < 4; ++i)
#pragma unroll
        for (int j = 0; j < 4; ++j) {
            int col = ccol0 + j * 16;
            if (EPI == 0) {
                if (col < Nreal) {
                    float* cp = C + zoff + (size_t)(crow0 + i * 16) * ldc + col;
#pragma unroll
                    for (int rr = 0; rr < 4; ++rr) cp[(size_t)rr * ldc] = acc[i][j][rr];
                }
            } else if (EPI == 2) {
                unsigned short* cx = (unsigned short*)C;
                unsigned short* cz = (unsigned short*)C2;
                if (col < 2048) {
#pragma unroll
                    for (int rr = 0; rr < 4; ++rr)
                        cx[(size_t)(crow0 + i * 16 + rr) * 2048 + col] = f2bf(acc[i][j][rr]);
                } else {
#pragma unroll
                    for (int rr = 0; rr < 4; ++rr)
                        cz[(size_t)(crow0 + i * 16 + rr) * 2048 + (col - 2048)] = f2bf(acc[i][j][rr]);
                }
            } else {  // EPI == 3
                unsigned short* cp = (unsigned short*)C2 + zoff + (size_t)(crow0 + i * 16) * ldc + col;
#pragma unroll
                for (int rr = 0; rr < 4; ++rr) cp[(size_t)rr * ldc] = f2h(acc[i][j][rr]);
            }
        }
}

// ---------------- fused: xp split-K reduce + dt_proj GEMM (f32) + softplus -> delta bf16 ----------------
// grid NROWS/DR_ROWS blocks; each block: 8 rows. Wdt f32 [64][2048] is L2-resident.
__global__ __launch_bounds__(256) void reduce_delta(const float* __restrict__ part,
                                                    const float* __restrict__ Wdt,
                                                    const float* __restrict__ dtb,
                                                    float* __restrict__ xp,
                                                    unsigned short* __restrict__ delta) {
    int r0 = blockIdx.x * DR_ROWS;
    __shared__ float dtr[DR_ROWS][64];
    for (int idx = threadIdx.x; idx < DR_ROWS * XPN; idx += 256) {
        int rr = idx / XPN, cc = idx - rr * XPN;
        size_t off = (size_t)(r0 + rr) * XPN + cc;
        float s = 0.f;
#pragma unroll
        for (int p = 0; p < 16; ++p) s += part[(size_t)p * ((size_t)NROWS * XPN) + off];
        xp[off] = s;
        if (cc < 64) dtr[rr][cc] = s;
    }
    __syncthreads();
    int c0 = threadIdx.x * 8;
    float acc[DR_ROWS][8] = {};
    for (int k = 0; k < 64; ++k) {
        float4 w0 = *(const float4*)(Wdt + (size_t)k * D_INNER + c0);
        float4 w1 = *(const float4*)(Wdt + (size_t)k * D_INNER + c0 + 4);
        float wv[8] = {w0.x, w0.y, w0.z, w0.w, w1.x, w1.y, w1.z, w1.w};
#pragma unroll
        for (int rr = 0; rr < DR_ROWS; ++rr) {
            float s = dtr[rr][k];
#pragma unroll
            for (int j = 0; j < 8; ++j) acc[rr][j] = fmaf(s, wv[j], acc[rr][j]);
        }
    }
    float4 b0 = *(const float4*)(dtb + c0);
    float4 b1 = *(const float4*)(dtb + c0 + 4);
    float bias[8] = {b0.x, b0.y, b0.z, b0.w, b1.x, b1.y, b1.z, b1.w};
#pragma unroll
    for (int rr = 0; rr < DR_ROWS; ++rr) {
        ushort4 o0, o1;
        unsigned short tmp[8];
#pragma unroll
        for (int j = 0; j < 8; ++j) {
            float v = acc[rr][j] + bias[j];
            v = (v > 20.f) ? v : log1pf(__expf(v));
            tmp[j] = f2bf(v);
        }
        o0.x = tmp[0]; o0.y = tmp[1]; o0.z = tmp[2]; o0.w = tmp[3];
        o1.x = tmp[4]; o1.y = tmp[5]; o1.z = tmp[6]; o1.w = tmp[7];
        unsigned short* dp = delta + (size_t)(r0 + rr) * D_INNER + c0;
        *(ushort4*)dp = o0;
        *(ushort4*)(dp + 4) = o1;
    }
}

// ---------------- split-K reduce for out (KS=4, f16 partials) ----------------
__global__ __launch_bounds__(256) void reduce_out(const unsigned short* __restrict__ part,
                                                  float* __restrict__ out) {
    int t = blockIdx.x * 256 + threadIdx.x;
    const size_t stride = (size_t)NROWS * D_MODEL;
    ushort4 p0 = ((const ushort4*)part)[t];
    ushort4 p1 = ((const ushort4*)(part + stride))[t];
    ushort4 p2 = ((const ushort4*)(part + 2 * stride))[t];
    ushort4 p3 = ((const ushort4*)(part + 3 * stride))[t];
    float4 o;
    o.x = h2f(p0.x) + h2f(p1.x) + h2f(p2.x) + h2f(p3.x);
    o.y = h2f(p0.y) + h2f(p1.y) + h2f(p2.y) + h2f(p3.y);
    o.z = h2f(p0.z) + h2f(p1.z) + h2f(p2.z) + h2f(p3.z);
    o.w = h2f(p0.w) + h2f(p1.w) + h2f(p2.w) + h2f(p3.w);
    ((float4*)out)[t] = o;
}

// ---------------- causal depthwise conv (k=4) + SiLU, bf16 in -> bf16 out ----------------
__global__ __launch_bounds__(256) void conv_silu_kernel(const unsigned short* __restrict__ xx,
                                                        const float* __restrict__ cw,
                                                        const float* __restrict__ cb,
                                                        unsigned short* __restrict__ outb) {
    int gid = blockIdx.x * 256 + threadIdx.x;
    int d4 = (gid & 511) << 2;
    int bl = gid >> 9;
    int l = bl & (LSEQ - 1);
    const unsigned short* base = xx + (size_t)bl * D_INNER + d4;
    ushort4 zr4 = {0, 0, 0, 0};
    ushort4 X0 = *(const ushort4*)base;
    ushort4 X1 = (l >= 1) ? *(const ushort4*)(base - D_INNER) : zr4;
    ushort4 X2 = (l >= 2) ? *(const ushort4*)(base - 2 * D_INNER) : zr4;
    ushort4 X3 = (l >= 3) ? *(const ushort4*)(base - 3 * D_INNER) : zr4;
    float4 bias = *(const float4*)(cb + d4);
    const float4* wv = (const float4*)(cw + (size_t)d4 * 4);
    float xs0[4] = {bf2f(X0.x), bf2f(X0.y), bf2f(X0.z), bf2f(X0.w)};
    float xs1[4] = {bf2f(X1.x), bf2f(X1.y), bf2f(X1.z), bf2f(X1.w)};
    float xs2[4] = {bf2f(X2.x), bf2f(X2.y), bf2f(X2.z), bf2f(X2.w)};
    float xs3[4] = {bf2f(X3.x), bf2f(X3.y), bf2f(X3.z), bf2f(X3.w)};
    float bs[4] = {bias.x, bias.y, bias.z, bias.w};
    ushort4 ob;
    unsigned short* obp = (unsigned short*)&ob;
#pragma unroll
    for (int e = 0; e < 4; ++e) {
        float4 we = wv[e];
        float acc = bs[e];
        acc = fmaf(we.w, xs0[e], acc);
        acc = fmaf(we.z, xs1[e], acc);
        acc = fmaf(we.y, xs2[e], acc);
        acc = fmaf(we.x, xs3[e], acc);
        obp[e] = f2bf(acc / (1.f + __expf(-acc)));
    }
    *(ushort4*)(outb + (size_t)bl * D_INNER + d4) = ob;
}

// ---------------- scan phase 1: per-chunk local scan (h0 = 0) ----------------
__global__ __launch_bounds__(256) void scan_local(const float* __restrict__ xp,
                                                  const unsigned short* __restrict__ delta,
                                                  const unsigned short* __restrict__ ub,
                                                  const float* __restrict__ A_log,
                                                  float* __restrict__ hst,
                                                  float* __restrict__ sdel) {
    int bc = blockIdx.x >> 3;
    int b = bc >> 5, c = bc & (NC - 1);
    int d = (blockIdx.x & 7) * 256 + threadIdx.x;
    int base_r = b * LSEQ + c * CL;
    __shared__ float Bsm[CL * 16];
    for (int e = threadIdx.x; e < CL * 16; e += 256) {
        int l = e >> 4, n = e & 15;
        Bsm[e] = xp[(size_t)(base_r + l) * XPN + DT_RANK + n];
    }
    __syncthreads();
    float Av[16];
    const float4* ap = (const float4*)(A_log + (size_t)d * 16);
#pragma unroll
    for (int qq = 0; qq < 4; ++qq) {
        float4 a = ap[qq];
        Av[4 * qq + 0] = -__expf(a.x); Av[4 * qq + 1] = -__expf(a.y);
        Av[4 * qq + 2] = -__expf(a.z); Av[4 * qq + 3] = -__expf(a.w);
    }
    float h[16] = {};
    float sd = 0.f;
    const unsigned short* dp = delta + (size_t)base_r * D_INNER + d;
    const unsigned short* up = ub + (size_t)base_r * D_INNER + d;
#pragma unroll 4
    for (int l = 0; l < CL; ++l) {
        float dv = bf2f(dp[(size_t)l * D_INNER]);
        float u = bf2f(up[(size_t)l * D_INNER]);
        float du = dv * u;
        sd += dv;
#pragma unroll
        for (int n = 0; n < 16; ++n) {
            float dA = __expf(dv * Av[n]);
            h[n] = fmaf(dA, h[n], du * Bsm[l * 16 + n]);
        }
    }
    size_t hi = ((size_t)(c * NB + b) * D_INNER + d) * 16;
#pragma unroll
    for (int qq = 0; qq < 4; ++qq) {
        float4 v = make_float4(h[4 * qq], h[4 * qq + 1], h[4 * qq + 2], h[4 * qq + 3]);
        *(float4*)(hst + hi + 4 * qq) = v;
    }
    sdel[(size_t)(c * NB + b) * D_INNER + d] = sd;
}

// ---------------- scan phase 2: cross-chunk combine ----------------
__global__ __launch_bounds__(256) void scan_combine(const float* __restrict__ A_log,
                                                    const float* __restrict__ sdel,
                                                    float* __restrict__ hst) {
    int t = blockIdx.x * 256 + threadIdx.x;
    int n = t & 15, d = (t >> 4) & (D_INNER - 1), b = t >> 15;
    float Avn = -__expf(A_log[(size_t)d * 16 + n]);
    float h = 0.f;
#pragma unroll 4
    for (int c = 0; c < NC; ++c) {
        size_t base = (size_t)(c * NB + b) * D_INNER + d;
        float* hp = hst + base * 16 + n;
        float S = sdel[base];
        float tmp = *hp;
        *hp = h;
        h = fmaf(__expf(Avn * S), h, tmp);
    }
}

// ---------------- scan phase 3: finalize, fuse silu(z) gate -> bf16 y ----------------
__global__ __launch_bounds__(256) void scan_final(const float* __restrict__ xp,
                                                  const unsigned short* __restrict__ delta,
                                                  const unsigned short* __restrict__ ub,
                                                  const unsigned short* __restrict__ zb,
                                                  const float* __restrict__ hst,
                                                  const float* __restrict__ A_log,
                                                  const float* __restrict__ Dp,
                                                  unsigned short* __restrict__ yb) {
    int bc = blockIdx.x >> 3;
    int b = bc >> 5, c = bc & (NC - 1);
    int d = (blockIdx.x & 7) * 256 + threadIdx.x;
    int base_r = b * LSEQ + c * CL;
    __shared__ float Bsm[CL * 16], Csm[CL * 16];
    for (int e = threadIdx.x; e < CL * 16; e += 256) {
        int l = e >> 4, n = e & 15;
        Bsm[e] = xp[(size_t)(base_r + l) * XPN + DT_RANK + n];
        Csm[e] = xp[(size_t)(base_r + l) * XPN + DT_RANK + 16 + n];
    }
    __syncthreads();
    float Av[16];
    const float4* ap = (const float4*)(A_log + (size_t)d * 16);
#pragma unroll
    for (int qq = 0; qq < 4; ++qq) {
        float4 a = ap[qq];
        Av[4 * qq + 0] = -__expf(a.x); Av[4 * qq + 1] = -__expf(a.y);
        Av[4 * qq + 2] = -__expf(a.z); Av[4 * qq + 3] = -__expf(a.w);
    }
    float h[16];
    size_t hi = ((size_t)(c * NB + b) * D_INNER + d) * 16;
#pragma unroll
    for (int qq = 0; qq < 4; ++qq) {
        float4 v = *(const float4*)(hst + hi + 4 * qq);
        h[4 * qq] = v.x; h[4 * qq + 1] = v.y; h[4 * qq + 2] = v.z; h[4 * qq + 3] = v.w;
    }
    float Dv = Dp[d];
    const unsigned short* dp = delta + (size_t)base_r * D_INNER + d;
    const unsigned short* up = ub + (size_t)base_r * D_INNER + d;
    const unsigned short* zp = zb + (size_t)base_r * D_INNER + d;
#pragma unroll 4
    for (int l = 0; l < CL; ++l) {
        float dv = bf2f(dp[(size_t)l * D_INNER]);
        float u = bf2f(up[(size_t)l * D_INNER]);
        float du = dv * u;
        float acc = 0.f;
#pragma unroll
        for (int n = 0; n < 16; ++n) {
            float dA = __expf(dv * Av[n]);
            h[n] = fmaf(dA, h[n], du * Bsm[l * 16 + n]);
            acc = fmaf(h[n], Csm[l * 16 + n], acc);
        }
        float yv = fmaf(u, Dv, acc);
        float zv = bf2f(zp[(size_t)l * D_INNER]);
        float sz = zv / (1.f + __expf(-zv));
        yb[(size_t)(base_r + l) * D_INNER + d] = f2bf(yv * sz);
    }
}

extern "C" void kernel_launch(void* const* d_in, const int* in_sizes, int n_in,
                              void* d_out, int out_size, void* d_ws, size_t ws_size,
                              hipStream_t stream) {
    const float* hidden = (const float*)d_in[0];
    const float* norm_w = (const float*)d_in[1];
    const float* norm_b = (const float*)d_in[2];
    const float* in_proj_w = (const float*)d_in[3];
    const float* conv_w = (const float*)d_in[4];
    const float* conv_b = (const float*)d_in[5];
    const float* x_proj_w = (const float*)d_in[6];
    const float* dt_proj_w = (const float*)d_in[7];
    const float* dt_proj_b = (const float*)d_in[8];
    const float* A_log = (const float*)d_in[9];
    const float* D_param = (const float*)d_in[10];
    const float* out_proj_w = (const float*)d_in[11];
    float* out = (float*)d_out;

    float* wsf = (float*)d_ws;
    // [0, 1,048,576):        hbufb bf16 (s2-3)  ->  xpbuf f32 + sdel (s6-9)
    unsigned short* hbufb = (unsigned short*)wsf;
    float* xpbuf = wsf;
    float* sdelbuf = wsf + 196608;
    // [1,048,576, 3,145,728): xb bf16 (s3-4) -> hst f32 (s7-9)
    unsigned short* xb = (unsigned short*)(wsf + 1048576);
    float* hst = wsf + 1048576;
    // [3,145,728, 5,242,880): zb bf16 (s3..s9)
    unsigned short* zb = (unsigned short*)(wsf + 3145728);
    // [5,242,880, 7,340,032): ub bf16 (s4..s9); yb aliases (s9-10)
    unsigned short* ub = (unsigned short*)(wsf + 5242880);
    unsigned short* yb = ub;
    // [7,340,032, 10,485,760): wAt bf16 (s1-3) -> xpart f32 (s5-6) -> opart f16 (s10-11, spills into dead wXt)
    unsigned short* wAt = (unsigned short*)(wsf + 7340032);
    float* xpart = wsf + 7340032;
    unsigned short* opart = (unsigned short*)(wsf + 7340032);
    // [10,485,760, 10,616,832): wXt bf16 (s1-5)
    unsigned short* wXt = (unsigned short*)(wsf + 10485760);
    // [11,665,408, 13,762,560): delta bf16 (s6-9)
    unsigned short* deltab = (unsigned short*)(wsf + 11665408);
    // [13,762,560, 14,811,136): wOt bf16 (s1-10)
    unsigned short* wOt = (unsigned short*)(wsf + 13762560);

    // 1. all weight casts, one dispatch
    wcast_all<<<6400, 256, 0, stream>>>(in_proj_w, wAt, x_proj_w, wXt, out_proj_w, wOt);

    // 2. LayerNorm -> bf16
    ln_kernel<<<NROWS, 256, 0, stream>>>(hidden, norm_w, norm_b, hbufb);

    // 3. xz = h @ in_proj_w : x-half bf16 -> xb, z-half bf16 -> zb
    gemm_bf16<2><<<dim3(4096 / 128, NROWS / 128, 1), 256, 0, stream>>>(
        hbufb, wAt, (float*)xb, zb, NROWS, 1024, 2048, 4096);

    // 4. conv + silu -> bf16 u
    conv_silu_kernel<<<(NROWS * D_INNER) / 1024, 256, 0, stream>>>(xb, conv_w, conv_b, ub);

    // 5. xp partials = u @ x_proj_w (split-K = 16)
    gemm_bf16<0><<<dim3(1, NROWS / 128, 16), 256, 0, stream>>>(
        ub, wXt, xpart, nullptr, NROWS, 2048, XPN, XPN);

    // 6. fused reduce + dt_proj + softplus -> xp f32, delta bf16
    reduce_delta<<<NROWS / DR_ROWS, 256, 0, stream>>>(xpart, dt_proj_w, dt_proj_b, xpbuf, deltab);

    // 7-9. chunked selective scan + fused gate -> bf16 y
    scan_local<<<NB * NC * (D_INNER / 256), 256, 0, stream>>>(
        xpbuf, deltab, ub, A_log, hst, sdelbuf);
    scan_combine<<<(NB * D_INNER * D_STATE) / 256, 256, 0, stream>>>(
        A_log, sdelbuf, hst);
    scan_final<<<NB * NC * (D_INNER / 256), 256, 0, stream>>>(
        xpbuf, deltab, ub, zb, hst, A_log, D_param, yb);

    // 10. out partials = y @ out_proj_w (split-K = 4, f16 partials)
    gemm_bf16<3><<<dim3(1024 / 128, NROWS / 128, 4), 256, 0, stream>>>(
        yb, wOt, nullptr, opart, NROWS, 2048, 1024, 1024);

    // 11. reduce f16 partials -> d_out
    reduce_out<<<(NROWS * D_MODEL / 4) / 256, 256, 0, stream>>>(opart, out);
}

// Round 8
// 181.085 us; speedup vs baseline: 1.1077x; 1.0705x over previous
//
#include <hip/hip_runtime.h>
#include <hip/hip_bf16.h>

#define D_MODEL 1024
#define D_INNER 2048
#define D_STATE 16
#define DT_RANK 64
#define NB 2
#define LSEQ 1024
#define NROWS (NB * LSEQ)
#define XPN 96
#define NC 32
#define CL 32

typedef __attribute__((ext_vector_type(8))) short bf16x8;
typedef __attribute__((ext_vector_type(4))) float f32x4;

__device__ __forceinline__ unsigned short f2bf(float x) {
    __hip_bfloat16 h = __float2bfloat16(x);
    return *reinterpret_cast<unsigned short*>(&h);
}
__device__ __forceinline__ float bf2f(unsigned short u) {
    unsigned int v = ((unsigned int)u) << 16;
    float f;
    __builtin_memcpy(&f, &v, 4);
    return f;
}
__device__ __forceinline__ unsigned short f2h(float x) {
    _Float16 h = (_Float16)x;
    unsigned short u;
    __builtin_memcpy(&u, &h, 2);
    return u;
}
__device__ __forceinline__ float h2f(unsigned short u) {
    _Float16 h;
    __builtin_memcpy(&h, &u, 2);
    return (float)h;
}

// ---------------- LayerNorm -> bf16 out ----------------
__global__ __launch_bounds__(256) void ln_kernel(const float* __restrict__ x,
                                                 const float* __restrict__ w,
                                                 const float* __restrict__ bnorm,
                                                 unsigned short* __restrict__ outb) {
    int row = blockIdx.x;
    const float4* xr = (const float4*)(x + (size_t)row * D_MODEL);
    float4 v = xr[threadIdx.x];
    float s = v.x + v.y + v.z + v.w;
    float sq = v.x * v.x + v.y * v.y + v.z * v.z + v.w * v.w;
#pragma unroll
    for (int off = 32; off > 0; off >>= 1) {
        s += __shfl_down(s, off);
        sq += __shfl_down(sq, off);
    }
    __shared__ float ws[4], wq[4];
    __shared__ float smu, srstd;
    int wave = threadIdx.x >> 6;
    if ((threadIdx.x & 63) == 0) { ws[wave] = s; wq[wave] = sq; }
    __syncthreads();
    if (threadIdx.x == 0) {
        float ts = ws[0] + ws[1] + ws[2] + ws[3];
        float tq = wq[0] + wq[1] + wq[2] + wq[3];
        float mu = ts * (1.f / D_MODEL);
        float var = tq * (1.f / D_MODEL) - mu * mu;
        smu = mu;
        srstd = rsqrtf(var + 1e-5f);
    }
    __syncthreads();
    float mu = smu, rstd = srstd;
    float4 wv = ((const float4*)w)[threadIdx.x];
    float4 bv = ((const float4*)bnorm)[threadIdx.x];
    ushort4 pk;
    pk.x = f2bf((v.x - mu) * rstd * wv.x + bv.x);
    pk.y = f2bf((v.y - mu) * rstd * wv.y + bv.y);
    pk.z = f2bf((v.z - mu) * rstd * wv.z + bv.z);
    pk.w = f2bf((v.w - mu) * rstd * wv.w + bv.w);
    *(ushort4*)(outb + (size_t)row * D_MODEL + threadIdx.x * 4) = pk;
}

// ---------------- all 4 weight casts in ONE dispatch ----------------
__global__ __launch_bounds__(256) void wcast_all(const float* __restrict__ W0, unsigned short* __restrict__ D0,
                                                 const float* __restrict__ W1, unsigned short* __restrict__ D1,
                                                 const float* __restrict__ W2, unsigned short* __restrict__ D2,
                                                 const float* __restrict__ W3, unsigned short* __restrict__ D3) {
    int bid = blockIdx.x;
    const float* W;
    unsigned short* Dst;
    int K, Nreal, bx, by;
    if (bid < 4096) { W = W0; Dst = D0; K = 1024; Nreal = 4096; bx = bid & 127; by = bid >> 7; }
    else if (bid < 4352) { int j = bid - 4096; W = W1; Dst = D1; K = 2048; Nreal = 96; bx = j & 3; by = j >> 2; }
    else if (bid < 6400) { int j = bid - 4352; W = W2; Dst = D2; K = 2048; Nreal = 1024; bx = j & 31; by = j >> 5; }
    else { int j = bid - 6400; W = W3; Dst = D3; K = 64; Nreal = 2048; bx = j & 63; by = j >> 6; }
    __shared__ float t[32][33];
    int tn = bx * 32, tk = by * 32;
    for (int e = threadIdx.x; e < 1024; e += 256) {
        int r = e >> 5, c = e & 31;
        int n = tn + c;
        t[r][c] = (n < Nreal) ? W[(size_t)(tk + r) * Nreal + n] : 0.f;
    }
    __syncthreads();
    for (int e = threadIdx.x; e < 1024; e += 256) {
        int r = e >> 5, c = e & 31;
        Dst[(size_t)(tn + r) * K + tk + c] = f2bf(t[c][r]);
    }
}

// ---------------- bf16 MFMA GEMM: C = A[M][K] @ Bt[N][K]^T ----------------
// EPI 0: f32 C (+split-K zoff). EPI 2: xz-split, both halves bf16 (x->C, z->C2).
// EPI 3: f16 partials into C2 (+split-K zoff). EPI 4: softplus(v+bias[col]) -> bf16 C2.
template <int EPI>
__global__ __launch_bounds__(256) void gemm_bf16(const unsigned short* __restrict__ A,
                                                 const unsigned short* __restrict__ Bt,
                                                 const float* __restrict__ bias,
                                                 float* __restrict__ C,
                                                 void* __restrict__ C2,
                                                 int M, int K, int ldc, int Nreal) {
    __shared__ unsigned short As[128 * 32];
    __shared__ unsigned short Bs[128 * 32];
    int nwg = gridDim.x * gridDim.y;
    int orig = blockIdx.y * gridDim.x + blockIdx.x;
    int q = nwg >> 3, r = nwg & 7;
    int xcd = orig & 7, idx = orig >> 3;
    int newid = (xcd < r ? xcd * (q + 1) : r * (q + 1) + (xcd - r) * q) + idx;
    int bx = newid % gridDim.x, by = newid / gridDim.x;

    int tid = threadIdx.x;
    int lane = tid & 63;
    int wave = tid >> 6;
    int wr = (wave >> 1) * 64, wc = (wave & 1) * 64;
    int bm = by * 128, bn = bx * 128;
    int kchunk = K / gridDim.z;
    int kbeg = blockIdx.z * kchunk;

    f32x4 acc[4][4];
#pragma unroll
    for (int i = 0; i < 4; ++i)
#pragma unroll
        for (int j = 0; j < 4; ++j) acc[i][j] = (f32x4){0.f, 0.f, 0.f, 0.f};

    int r0 = tid >> 2;
    int c0 = (tid & 3) * 8;
    const unsigned short* a0 = A + (size_t)(bm + r0) * K + c0;
    const unsigned short* a1 = A + (size_t)(bm + 64 + r0) * K + c0;
    const unsigned short* b0 = Bt + (size_t)(bn + r0) * K + c0;
    const unsigned short* b1 = Bt + (size_t)(bn + 64 + r0) * K + c0;
    unsigned short* asw0 = As + (size_t)(tid & ~63) * 8;
    unsigned short* asw1 = As + 2048 + (size_t)(tid & ~63) * 8;
    unsigned short* bsw0 = Bs + (size_t)(tid & ~63) * 8;
    unsigned short* bsw1 = Bs + 2048 + (size_t)(tid & ~63) * 8;

    int ar = lane & 15;
    int ko = (lane >> 4) * 8;

    for (int k0 = kbeg; k0 < kbeg + kchunk; k0 += 32) {
        __syncthreads();
        __builtin_amdgcn_global_load_lds((const __attribute__((address_space(1))) void*)(a0 + k0),
                                         (__attribute__((address_space(3))) void*)asw0, 16, 0, 0);
        __builtin_amdgcn_global_load_lds((const __attribute__((address_space(1))) void*)(a1 + k0),
                                         (__attribute__((address_space(3))) void*)asw1, 16, 0, 0);
        __builtin_amdgcn_global_load_lds((const __attribute__((address_space(1))) void*)(b0 + k0),
                                         (__attribute__((address_space(3))) void*)bsw0, 16, 0, 0);
        __builtin_amdgcn_global_load_lds((const __attribute__((address_space(1))) void*)(b1 + k0),
                                         (__attribute__((address_space(3))) void*)bsw1, 16, 0, 0);
        __syncthreads();
        bf16x8 af[4], bfr[4];
#pragma unroll
        for (int i = 0; i < 4; ++i)
            af[i] = *(const bf16x8*)&As[(size_t)(wr + i * 16 + ar) * 32 + ko];
#pragma unroll
        for (int j = 0; j < 4; ++j)
            bfr[j] = *(const bf16x8*)&Bs[(size_t)(wc + j * 16 + ar) * 32 + ko];
#pragma unroll
        for (int i = 0; i < 4; ++i)
#pragma unroll
            for (int j = 0; j < 4; ++j)
                acc[i][j] = __builtin_amdgcn_mfma_f32_16x16x32_bf16(af[i], bfr[j], acc[i][j], 0, 0, 0);
    }

    int crow0 = bm + wr + (lane >> 4) * 4;
    int ccol0 = bn + wc + (lane & 15);
    size_t zoff = (size_t)blockIdx.z * (size_t)M * ldc;
#pragma unroll
    for (int i = 0; i < 4; ++i)
#pragma unroll
        for (int j = 0; j < 4; ++j) {
            int col = ccol0 + j * 16;
            if (EPI == 0) {
                if (col < Nreal) {
                    float* cp = C + zoff + (size_t)(crow0 + i * 16) * ldc + col;
#pragma unroll
                    for (int rr = 0; rr < 4; ++rr) cp[(size_t)rr * ldc] = acc[i][j][rr];
                }
            } else if (EPI == 2) {
                unsigned short* cx = (unsigned short*)C;
                unsigned short* cz = (unsigned short*)C2;
                if (col < 2048) {
#pragma unroll
                    for (int rr = 0; rr < 4; ++rr)
                        cx[(size_t)(crow0 + i * 16 + rr) * 2048 + col] = f2bf(acc[i][j][rr]);
                } else {
#pragma unroll
                    for (int rr = 0; rr < 4; ++rr)
                        cz[(size_t)(crow0 + i * 16 + rr) * 2048 + (col - 2048)] = f2bf(acc[i][j][rr]);
                }
            } else if (EPI == 3) {
                unsigned short* cp = (unsigned short*)C2 + zoff + (size_t)(crow0 + i * 16) * ldc + col;
#pragma unroll
                for (int rr = 0; rr < 4; ++rr) cp[(size_t)rr * ldc] = f2h(acc[i][j][rr]);
            } else {  // EPI == 4: softplus(v + bias) -> bf16  (row offset FIXED: + i*16)
                float bv = bias[col];
                unsigned short* cp = (unsigned short*)C2 + (size_t)(crow0 + i * 16) * ldc + col;
#pragma unroll
                for (int rr = 0; rr < 4; ++rr) {
                    float v = acc[i][j][rr] + bv;
                    v = (v > 20.f) ? v : log1pf(__expf(v));
                    cp[(size_t)rr * ldc] = f2bf(v);
                }
            }
        }
}

// ---------------- split-K reduce for xp (KS=16) + bf16 dt_r extract ----------------
__global__ __launch_bounds__(256) void reduce_xp(const float* __restrict__ part,
                                                 float* __restrict__ xp,
                                                 unsigned short* __restrict__ dtr) {
    int t = blockIdx.x * 256 + threadIdx.x;
    float s = 0.f;
#pragma unroll
    for (int k = 0; k < 16; ++k) s += part[(size_t)k * ((size_t)NROWS * XPN) + t];
    xp[t] = s;
    int row = t / 96, col = t - row * 96;
    if (col < 64) dtr[(size_t)row * 64 + col] = f2bf(s);
}

// ---------------- split-K reduce for out (KS=4, f16 partials) ----------------
__global__ __launch_bounds__(256) void reduce_out(const unsigned short* __restrict__ part,
                                                  float* __restrict__ out) {
    int t = blockIdx.x * 256 + threadIdx.x;
    const size_t stride = (size_t)NROWS * D_MODEL;
    ushort4 p0 = ((const ushort4*)part)[t];
    ushort4 p1 = ((const ushort4*)(part + stride))[t];
    ushort4 p2 = ((const ushort4*)(part + 2 * stride))[t];
    ushort4 p3 = ((const ushort4*)(part + 3 * stride))[t];
    float4 o;
    o.x = h2f(p0.x) + h2f(p1.x) + h2f(p2.x) + h2f(p3.x);
    o.y = h2f(p0.y) + h2f(p1.y) + h2f(p2.y) + h2f(p3.y);
    o.z = h2f(p0.z) + h2f(p1.z) + h2f(p2.z) + h2f(p3.z);
    o.w = h2f(p0.w) + h2f(p1.w) + h2f(p2.w) + h2f(p3.w);
    ((float4*)out)[t] = o;
}

// ---------------- causal depthwise conv (k=4) + SiLU, bf16 in -> bf16 out ----------------
__global__ __launch_bounds__(256) void conv_silu_kernel(const unsigned short* __restrict__ xx,
                                                        const float* __restrict__ cw,
                                                        const float* __restrict__ cb,
                                                        unsigned short* __restrict__ outb) {
    int gid = blockIdx.x * 256 + threadIdx.x;
    int d4 = (gid & 511) << 2;
    int bl = gid >> 9;
    int l = bl & (LSEQ - 1);
    const unsigned short* base = xx + (size_t)bl * D_INNER + d4;
    ushort4 zr4 = {0, 0, 0, 0};
    ushort4 X0 = *(const ushort4*)base;
    ushort4 X1 = (l >= 1) ? *(const ushort4*)(base - D_INNER) : zr4;
    ushort4 X2 = (l >= 2) ? *(const ushort4*)(base - 2 * D_INNER) : zr4;
    ushort4 X3 = (l >= 3) ? *(const ushort4*)(base - 3 * D_INNER) : zr4;
    float4 bias = *(const float4*)(cb + d4);
    const float4* wv = (const float4*)(cw + (size_t)d4 * 4);
    float xs0[4] = {bf2f(X0.x), bf2f(X0.y), bf2f(X0.z), bf2f(X0.w)};
    float xs1[4] = {bf2f(X1.x), bf2f(X1.y), bf2f(X1.z), bf2f(X1.w)};
    float xs2[4] = {bf2f(X2.x), bf2f(X2.y), bf2f(X2.z), bf2f(X2.w)};
    float xs3[4] = {bf2f(X3.x), bf2f(X3.y), bf2f(X3.z), bf2f(X3.w)};
    float bs[4] = {bias.x, bias.y, bias.z, bias.w};
    ushort4 ob;
    unsigned short* obp = (unsigned short*)&ob;
#pragma unroll
    for (int e = 0; e < 4; ++e) {
        float4 we = wv[e];
        float acc = bs[e];
        acc = fmaf(we.w, xs0[e], acc);
        acc = fmaf(we.z, xs1[e], acc);
        acc = fmaf(we.y, xs2[e], acc);
        acc = fmaf(we.x, xs3[e], acc);
        obp[e] = f2bf(acc / (1.f + __expf(-acc)));
    }
    *(ushort4*)(outb + (size_t)bl * D_INNER + d4) = ob;
}

// ---------------- scan phase 1: per-chunk local scan (h0 = 0) ----------------
__global__ __launch_bounds__(256) void scan_local(const float* __restrict__ xp,
                                                  const unsigned short* __restrict__ delta,
                                                  const unsigned short* __restrict__ ub,
                                                  const float* __restrict__ A_log,
                                                  float* __restrict__ hst,
                                                  float* __restrict__ sdel) {
    int bc = blockIdx.x >> 3;
    int b = bc >> 5, c = bc & (NC - 1);
    int d = (blockIdx.x & 7) * 256 + threadIdx.x;
    int base_r = b * LSEQ + c * CL;
    __shared__ float Bsm[CL * 16];
    for (int e = threadIdx.x; e < CL * 16; e += 256) {
        int l = e >> 4, n = e & 15;
        Bsm[e] = xp[(size_t)(base_r + l) * XPN + DT_RANK + n];
    }
    __syncthreads();
    float Av[16];
    const float4* ap = (const float4*)(A_log + (size_t)d * 16);
#pragma unroll
    for (int qq = 0; qq < 4; ++qq) {
        float4 a = ap[qq];
        Av[4 * qq + 0] = -__expf(a.x); Av[4 * qq + 1] = -__expf(a.y);
        Av[4 * qq + 2] = -__expf(a.z); Av[4 * qq + 3] = -__expf(a.w);
    }
    float h[16] = {};
    float sd = 0.f;
    const unsigned short* dp = delta + (size_t)base_r * D_INNER + d;
    const unsigned short* up = ub + (size_t)base_r * D_INNER + d;
#pragma unroll 4
    for (int l = 0; l < CL; ++l) {
        float dv = bf2f(dp[(size_t)l * D_INNER]);
        float u = bf2f(up[(size_t)l * D_INNER]);
        float du = dv * u;
        sd += dv;
#pragma unroll
        for (int n = 0; n < 16; ++n) {
            float dA = __expf(dv * Av[n]);
            h[n] = fmaf(dA, h[n], du * Bsm[l * 16 + n]);
        }
    }
    size_t hi = ((size_t)(c * NB + b) * D_INNER + d) * 16;
#pragma unroll
    for (int qq = 0; qq < 4; ++qq) {
        float4 v = make_float4(h[4 * qq], h[4 * qq + 1], h[4 * qq + 2], h[4 * qq + 3]);
        *(float4*)(hst + hi + 4 * qq) = v;
    }
    sdel[(size_t)(c * NB + b) * D_INNER + d] = sd;
}

// ---------------- scan phase 2: cross-chunk combine ----------------
__global__ __launch_bounds__(256) void scan_combine(const float* __restrict__ A_log,
                                                    const float* __restrict__ sdel,
                                                    float* __restrict__ hst) {
    int t = blockIdx.x * 256 + threadIdx.x;
    int n = t & 15, d = (t >> 4) & (D_INNER - 1), b = t >> 15;
    float Avn = -__expf(A_log[(size_t)d * 16 + n]);
    float h = 0.f;
#pragma unroll 4
    for (int c = 0; c < NC; ++c) {
        size_t base = (size_t)(c * NB + b) * D_INNER + d;
        float* hp = hst + base * 16 + n;
        float S = sdel[base];
        float tmp = *hp;
        *hp = h;
        h = fmaf(__expf(Avn * S), h, tmp);
    }
}

// ---------------- scan phase 3: finalize, fuse silu(z) gate -> bf16 y ----------------
__global__ __launch_bounds__(256) void scan_final(const float* __restrict__ xp,
                                                  const unsigned short* __restrict__ delta,
                                                  const unsigned short* __restrict__ ub,
                                                  const unsigned short* __restrict__ zb,
                                                  const float* __restrict__ hst,
                                                  const float* __restrict__ A_log,
                                                  const float* __restrict__ Dp,
                                                  unsigned short* __restrict__ yb) {
    int bc = blockIdx.x >> 3;
    int b = bc >> 5, c = bc & (NC - 1);
    int d = (blockIdx.x & 7) * 256 + threadIdx.x;
    int base_r = b * LSEQ + c * CL;
    __shared__ float Bsm[CL * 16], Csm[CL * 16];
    for (int e = threadIdx.x; e < CL * 16; e += 256) {
        int l = e >> 4, n = e & 15;
        Bsm[e] = xp[(size_t)(base_r + l) * XPN + DT_RANK + n];
        Csm[e] = xp[(size_t)(base_r + l) * XPN + DT_RANK + 16 + n];
    }
    __syncthreads();
    float Av[16];
    const float4* ap = (const float4*)(A_log + (size_t)d * 16);
#pragma unroll
    for (int qq = 0; qq < 4; ++qq) {
        float4 a = ap[qq];
        Av[4 * qq + 0] = -__expf(a.x); Av[4 * qq + 1] = -__expf(a.y);
        Av[4 * qq + 2] = -__expf(a.z); Av[4 * qq + 3] = -__expf(a.w);
    }
    float h[16];
    size_t hi = ((size_t)(c * NB + b) * D_INNER + d) * 16;
#pragma unroll
    for (int qq = 0; qq < 4; ++qq) {
        float4 v = *(const float4*)(hst + hi + 4 * qq);
        h[4 * qq] = v.x; h[4 * qq + 1] = v.y; h[4 * qq + 2] = v.z; h[4 * qq + 3] = v.w;
    }
    float Dv = Dp[d];
    const unsigned short* dp = delta + (size_t)base_r * D_INNER + d;
    const unsigned short* up = ub + (size_t)base_r * D_INNER + d;
    const unsigned short* zp = zb + (size_t)base_r * D_INNER + d;
#pragma unroll 4
    for (int l = 0; l < CL; ++l) {
        float dv = bf2f(dp[(size_t)l * D_INNER]);
        float u = bf2f(up[(size_t)l * D_INNER]);
        float du = dv * u;
        float acc = 0.f;
#pragma unroll
        for (int n = 0; n < 16; ++n) {
            float dA = __expf(dv * Av[n]);
            h[n] = fmaf(dA, h[n], du * Bsm[l * 16 + n]);
            acc = fmaf(h[n], Csm[l * 16 + n], acc);
        }
        float yv = fmaf(u, Dv, acc);
        float zv = bf2f(zp[(size_t)l * D_INNER]);
        float sz = zv / (1.f + __expf(-zv));
        yb[(size_t)(base_r + l) * D_INNER + d] = f2bf(yv * sz);
    }
}

extern "C" void kernel_launch(void* const* d_in, const int* in_sizes, int n_in,
                              void* d_out, int out_size, void* d_ws, size_t ws_size,
                              hipStream_t stream) {
    const float* hidden = (const float*)d_in[0];
    const float* norm_w = (const float*)d_in[1];
    const float* norm_b = (const float*)d_in[2];
    const float* in_proj_w = (const float*)d_in[3];
    const float* conv_w = (const float*)d_in[4];
    const float* conv_b = (const float*)d_in[5];
    const float* x_proj_w = (const float*)d_in[6];
    const float* dt_proj_w = (const float*)d_in[7];
    const float* dt_proj_b = (const float*)d_in[8];
    const float* A_log = (const float*)d_in[9];
    const float* D_param = (const float*)d_in[10];
    const float* out_proj_w = (const float*)d_in[11];
    float* out = (float*)d_out;

    float* wsf = (float*)d_ws;
    unsigned short* hbufb = (unsigned short*)wsf;
    float* xpbuf = wsf;
    float* sdelbuf = wsf + 196608;
    unsigned short* xb = (unsigned short*)(wsf + 1048576);
    float* hst = wsf + 1048576;
    unsigned short* zb = (unsigned short*)(wsf + 3145728);
    unsigned short* ub = (unsigned short*)(wsf + 5242880);
    unsigned short* yb = ub;
    unsigned short* wAt = (unsigned short*)(wsf + 7340032);
    float* xpart = wsf + 7340032;
    unsigned short* opart = (unsigned short*)(wsf + 7340032);
    unsigned short* wXt = (unsigned short*)(wsf + 10485760);
    unsigned short* wDt = (unsigned short*)(wsf + 10616832);
    unsigned short* dtrb = (unsigned short*)(wsf + 10682368);
    unsigned short* deltab = (unsigned short*)(wsf + 11665408);
    unsigned short* wOt = (unsigned short*)(wsf + 13762560);

    // 1. all weight casts, one dispatch
    wcast_all<<<6528, 256, 0, stream>>>(in_proj_w, wAt, x_proj_w, wXt, out_proj_w, wOt,
                                        dt_proj_w, wDt);

    // 2. LayerNorm -> bf16
    ln_kernel<<<NROWS, 256, 0, stream>>>(hidden, norm_w, norm_b, hbufb);

    // 3. xz = h @ in_proj_w : x-half bf16 -> xb, z-half bf16 -> zb
    gemm_bf16<2><<<dim3(4096 / 128, NROWS / 128, 1), 256, 0, stream>>>(
        hbufb, wAt, nullptr, (float*)xb, zb, NROWS, 1024, 2048, 4096);

    // 4. conv + silu -> bf16 u
    conv_silu_kernel<<<(NROWS * D_INNER) / 1024, 256, 0, stream>>>(xb, conv_w, conv_b, ub);

    // 5. xp partials = u @ x_proj_w (split-K = 16)
    gemm_bf16<0><<<dim3(1, NROWS / 128, 16), 256, 0, stream>>>(
        ub, wXt, nullptr, xpart, nullptr, NROWS, 2048, XPN, XPN);

    // 6. reduce partials -> xp f32 + dt_r bf16
    reduce_xp<<<(NROWS * XPN) / 256, 256, 0, stream>>>(xpart, xpbuf, dtrb);

    // 6b. delta = softplus(dt_r @ dt_proj_w + b) -> bf16 (MFMA)
    gemm_bf16<4><<<dim3(D_INNER / 128, NROWS / 128, 1), 256, 0, stream>>>(
        dtrb, wDt, dt_proj_b, nullptr, deltab, NROWS, 64, D_INNER, D_INNER);

    // 7-9. chunked selective scan + fused gate -> bf16 y
    scan_local<<<NB * NC * (D_INNER / 256), 256, 0, stream>>>(
        xpbuf, deltab, ub, A_log, hst, sdelbuf);
    scan_combine<<<(NB * D_INNER * D_STATE) / 256, 256, 0, stream>>>(
        A_log, sdelbuf, hst);
    scan_final<<<NB * NC * (D_INNER / 256), 256, 0, stream>>>(
        xpbuf, deltab, ub, zb, hst, A_log, D_param, yb);

    // 10. out partials = y @ out_proj_w (split-K = 4, f16 partials)
    gemm_bf16<3><<<dim3(1024 / 128, NROWS / 128, 4), 256, 0, stream>>>(
        yb, wOt, nullptr, nullptr, opart, NROWS, 2048, 1024, 1024);

    // 11. reduce f16 partials -> d_out
    reduce_out<<<(NROWS * D_MODEL / 4) / 256, 256, 0, stream>>>(opart, out);
}

// Round 9
// 181.074 us; speedup vs baseline: 1.1077x; 1.0001x over previous
//
#include <hip/hip_runtime.h>
#include <hip/hip_bf16.h>

#define D_MODEL 1024
#define D_INNER 2048
#define D_STATE 16
#define DT_RANK 64
#define NB 2
#define LSEQ 1024
#define NROWS (NB * LSEQ)
#define XPN 96
#define NC 32
#define CL 32

typedef __attribute__((ext_vector_type(8))) short bf16x8;
typedef __attribute__((ext_vector_type(4))) float f32x4;

__device__ __forceinline__ unsigned short f2bf(float x) {
    __hip_bfloat16 h = __float2bfloat16(x);
    return *reinterpret_cast<unsigned short*>(&h);
}
__device__ __forceinline__ float bf2f(unsigned short u) {
    unsigned int v = ((unsigned int)u) << 16;
    float f;
    __builtin_memcpy(&f, &v, 4);
    return f;
}
__device__ __forceinline__ unsigned short f2h(float x) {
    _Float16 h = (_Float16)x;
    unsigned short u;
    __builtin_memcpy(&u, &h, 2);
    return u;
}
__device__ __forceinline__ float h2f(unsigned short u) {
    _Float16 h;
    __builtin_memcpy(&h, &u, 2);
    return (float)h;
}

// ---------------- LayerNorm -> bf16 out ----------------
__global__ __launch_bounds__(256) void ln_kernel(const float* __restrict__ x,
                                                 const float* __restrict__ w,
                                                 const float* __restrict__ bnorm,
                                                 unsigned short* __restrict__ outb) {
    int row = blockIdx.x;
    const float4* xr = (const float4*)(x + (size_t)row * D_MODEL);
    float4 v = xr[threadIdx.x];
    float s = v.x + v.y + v.z + v.w;
    float sq = v.x * v.x + v.y * v.y + v.z * v.z + v.w * v.w;
#pragma unroll
    for (int off = 32; off > 0; off >>= 1) {
        s += __shfl_down(s, off);
        sq += __shfl_down(sq, off);
    }
    __shared__ float ws[4], wq[4];
    __shared__ float smu, srstd;
    int wave = threadIdx.x >> 6;
    if ((threadIdx.x & 63) == 0) { ws[wave] = s; wq[wave] = sq; }
    __syncthreads();
    if (threadIdx.x == 0) {
        float ts = ws[0] + ws[1] + ws[2] + ws[3];
        float tq = wq[0] + wq[1] + wq[2] + wq[3];
        float mu = ts * (1.f / D_MODEL);
        float var = tq * (1.f / D_MODEL) - mu * mu;
        smu = mu;
        srstd = rsqrtf(var + 1e-5f);
    }
    __syncthreads();
    float mu = smu, rstd = srstd;
    float4 wv = ((const float4*)w)[threadIdx.x];
    float4 bv = ((const float4*)bnorm)[threadIdx.x];
    ushort4 pk;
    pk.x = f2bf((v.x - mu) * rstd * wv.x + bv.x);
    pk.y = f2bf((v.y - mu) * rstd * wv.y + bv.y);
    pk.z = f2bf((v.z - mu) * rstd * wv.z + bv.z);
    pk.w = f2bf((v.w - mu) * rstd * wv.w + bv.w);
    *(ushort4*)(outb + (size_t)row * D_MODEL + threadIdx.x * 4) = pk;
}

// ---------------- all 4 weight casts in ONE dispatch ----------------
__global__ __launch_bounds__(256) void wcast_all(const float* __restrict__ W0, unsigned short* __restrict__ D0,
                                                 const float* __restrict__ W1, unsigned short* __restrict__ D1,
                                                 const float* __restrict__ W2, unsigned short* __restrict__ D2,
                                                 const float* __restrict__ W3, unsigned short* __restrict__ D3) {
    int bid = blockIdx.x;
    const float* W;
    unsigned short* Dst;
    int K, Nreal, bx, by;
    if (bid < 4096) { W = W0; Dst = D0; K = 1024; Nreal = 4096; bx = bid & 127; by = bid >> 7; }
    else if (bid < 4352) { int j = bid - 4096; W = W1; Dst = D1; K = 2048; Nreal = 96; bx = j & 3; by = j >> 2; }
    else if (bid < 6400) { int j = bid - 4352; W = W2; Dst = D2; K = 2048; Nreal = 1024; bx = j & 31; by = j >> 5; }
    else { int j = bid - 6400; W = W3; Dst = D3; K = 64; Nreal = 2048; bx = j & 63; by = j >> 6; }
    __shared__ float t[32][33];
    int tn = bx * 32, tk = by * 32;
    for (int e = threadIdx.x; e < 1024; e += 256) {
        int r = e >> 5, c = e & 31;
        int n = tn + c;
        t[r][c] = (n < Nreal) ? W[(size_t)(tk + r) * Nreal + n] : 0.f;
    }
    __syncthreads();
    for (int e = threadIdx.x; e < 1024; e += 256) {
        int r = e >> 5, c = e & 31;
        Dst[(size_t)(tn + r) * K + tk + c] = f2bf(t[c][r]);
    }
}

// ---------------- bf16 MFMA GEMM: C = A[M][K] @ Bt[N][K]^T ----------------
// EPI 0: f32 C (+split-K zoff). EPI 2: xz-split, both halves bf16 (x->C, z->C2).
// EPI 3: f16 partials into C2 (+split-K zoff). EPI 4: softplus(v+bias[col]) -> bf16 C2.
template <int EPI>
__global__ __launch_bounds__(256) void gemm_bf16(const unsigned short* __restrict__ A,
                                                 const unsigned short* __restrict__ Bt,
                                                 const float* __restrict__ bias,
                                                 float* __restrict__ C,
                                                 void* __restrict__ C2,
                                                 int M, int K, int ldc, int Nreal) {
    __shared__ unsigned short As[128 * 32];
    __shared__ unsigned short Bs[128 * 32];
    int nwg = gridDim.x * gridDim.y;
    int orig = blockIdx.y * gridDim.x + blockIdx.x;
    int q = nwg >> 3, r = nwg & 7;
    int xcd = orig & 7, idx = orig >> 3;
    int newid = (xcd < r ? xcd * (q + 1) : r * (q + 1) + (xcd - r) * q) + idx;
    int bx = newid % gridDim.x, by = newid / gridDim.x;

    int tid = threadIdx.x;
    int lane = tid & 63;
    int wave = tid >> 6;
    int wr = (wave >> 1) * 64, wc = (wave & 1) * 64;
    int bm = by * 128, bn = bx * 128;
    int kchunk = K / gridDim.z;
    int kbeg = blockIdx.z * kchunk;

    f32x4 acc[4][4];
#pragma unroll
    for (int i = 0; i < 4; ++i)
#pragma unroll
        for (int j = 0; j < 4; ++j) acc[i][j] = (f32x4){0.f, 0.f, 0.f, 0.f};

    int r0 = tid >> 2;
    int c0 = (tid & 3) * 8;
    const unsigned short* a0 = A + (size_t)(bm + r0) * K + c0;
    const unsigned short* a1 = A + (size_t)(bm + 64 + r0) * K + c0;
    const unsigned short* b0 = Bt + (size_t)(bn + r0) * K + c0;
    const unsigned short* b1 = Bt + (size_t)(bn + 64 + r0) * K + c0;
    unsigned short* asw0 = As + (size_t)(tid & ~63) * 8;
    unsigned short* asw1 = As + 2048 + (size_t)(tid & ~63) * 8;
    unsigned short* bsw0 = Bs + (size_t)(tid & ~63) * 8;
    unsigned short* bsw1 = Bs + 2048 + (size_t)(tid & ~63) * 8;

    int ar = lane & 15;
    int ko = (lane >> 4) * 8;

    for (int k0 = kbeg; k0 < kbeg + kchunk; k0 += 32) {
        __syncthreads();
        __builtin_amdgcn_global_load_lds((const __attribute__((address_space(1))) void*)(a0 + k0),
                                         (__attribute__((address_space(3))) void*)asw0, 16, 0, 0);
        __builtin_amdgcn_global_load_lds((const __attribute__((address_space(1))) void*)(a1 + k0),
                                         (__attribute__((address_space(3))) void*)asw1, 16, 0, 0);
        __builtin_amdgcn_global_load_lds((const __attribute__((address_space(1))) void*)(b0 + k0),
                                         (__attribute__((address_space(3))) void*)bsw0, 16, 0, 0);
        __builtin_amdgcn_global_load_lds((const __attribute__((address_space(1))) void*)(b1 + k0),
                                         (__attribute__((address_space(3))) void*)bsw1, 16, 0, 0);
        __syncthreads();
        bf16x8 af[4], bfr[4];
#pragma unroll
        for (int i = 0; i < 4; ++i)
            af[i] = *(const bf16x8*)&As[(size_t)(wr + i * 16 + ar) * 32 + ko];
#pragma unroll
        for (int j = 0; j < 4; ++j)
            bfr[j] = *(const bf16x8*)&Bs[(size_t)(wc + j * 16 + ar) * 32 + ko];
#pragma unroll
        for (int i = 0; i < 4; ++i)
#pragma unroll
            for (int j = 0; j < 4; ++j)
                acc[i][j] = __builtin_amdgcn_mfma_f32_16x16x32_bf16(af[i], bfr[j], acc[i][j], 0, 0, 0);
    }

    int crow0 = bm + wr + (lane >> 4) * 4;
    int ccol0 = bn + wc + (lane & 15);
    size_t zoff = (size_t)blockIdx.z * (size_t)M * ldc;
#pragma unroll
    for (int i = 0; i < 4; ++i)
#pragma unroll
        for (int j = 0; j < 4; ++j) {
            int col = ccol0 + j * 16;
            if (EPI == 0) {
                if (col < Nreal) {
                    float* cp = C + zoff + (size_t)(crow0 + i * 16) * ldc + col;
#pragma unroll
                    for (int rr = 0; rr < 4; ++rr) cp[(size_t)rr * ldc] = acc[i][j][rr];
                }
            } else if (EPI == 2) {
                unsigned short* cx = (unsigned short*)C;
                unsigned short* cz = (unsigned short*)C2;
                if (col < 2048) {
#pragma unroll
                    for (int rr = 0; rr < 4; ++rr)
                        cx[(size_t)(crow0 + i * 16 + rr) * 2048 + col] = f2bf(acc[i][j][rr]);
                } else {
#pragma unroll
                    for (int rr = 0; rr < 4; ++rr)
                        cz[(size_t)(crow0 + i * 16 + rr) * 2048 + (col - 2048)] = f2bf(acc[i][j][rr]);
                }
            } else if (EPI == 3) {
                unsigned short* cp = (unsigned short*)C2 + zoff + (size_t)(crow0 + i * 16) * ldc + col;
#pragma unroll
                for (int rr = 0; rr < 4; ++rr) cp[(size_t)rr * ldc] = f2h(acc[i][j][rr]);
            } else {  // EPI == 4: softplus(v + bias) -> bf16  (row offset FIXED: + i*16)
                float bv = bias[col];
                unsigned short* cp = (unsigned short*)C2 + (size_t)(crow0 + i * 16) * ldc + col;
#pragma unroll
                for (int rr = 0; rr < 4; ++rr) {
                    float v = acc[i][j][rr] + bv;
                    v = (v > 20.f) ? v : log1pf(__expf(v));
                    cp[(size_t)rr * ldc] = f2bf(v);
                }
            }
        }
}

// ---------------- split-K reduce for xp (KS=16) + bf16 dt_r extract ----------------
__global__ __launch_bounds__(256) void reduce_xp(const float* __restrict__ part,
                                                 float* __restrict__ xp,
                                                 unsigned short* __restrict__ dtr) {
    int t = blockIdx.x * 256 + threadIdx.x;
    float s = 0.f;
#pragma unroll
    for (int k = 0; k < 16; ++k) s += part[(size_t)k * ((size_t)NROWS * XPN) + t];
    xp[t] = s;
    int row = t / 96, col = t - row * 96;
    if (col < 64) dtr[(size_t)row * 64 + col] = f2bf(s);
}

// ---------------- split-K reduce for out (KS=4, f16 partials) ----------------
__global__ __launch_bounds__(256) void reduce_out(const unsigned short* __restrict__ part,
                                                  float* __restrict__ out) {
    int t = blockIdx.x * 256 + threadIdx.x;
    const size_t stride = (size_t)NROWS * D_MODEL;
    ushort4 p0 = ((const ushort4*)part)[t];
    ushort4 p1 = ((const ushort4*)(part + stride))[t];
    ushort4 p2 = ((const ushort4*)(part + 2 * stride))[t];
    ushort4 p3 = ((const ushort4*)(part + 3 * stride))[t];
    float4 o;
    o.x = h2f(p0.x) + h2f(p1.x) + h2f(p2.x) + h2f(p3.x);
    o.y = h2f(p0.y) + h2f(p1.y) + h2f(p2.y) + h2f(p3.y);
    o.z = h2f(p0.z) + h2f(p1.z) + h2f(p2.z) + h2f(p3.z);
    o.w = h2f(p0.w) + h2f(p1.w) + h2f(p2.w) + h2f(p3.w);
    ((float4*)out)[t] = o;
}

// ---------------- causal depthwise conv (k=4) + SiLU, bf16 in -> bf16 out ----------------
__global__ __launch_bounds__(256) void conv_silu_kernel(const unsigned short* __restrict__ xx,
                                                        const float* __restrict__ cw,
                                                        const float* __restrict__ cb,
                                                        unsigned short* __restrict__ outb) {
    int gid = blockIdx.x * 256 + threadIdx.x;
    int d4 = (gid & 511) << 2;
    int bl = gid >> 9;
    int l = bl & (LSEQ - 1);
    const unsigned short* base = xx + (size_t)bl * D_INNER + d4;
    ushort4 zr4 = {0, 0, 0, 0};
    ushort4 X0 = *(const ushort4*)base;
    ushort4 X1 = (l >= 1) ? *(const ushort4*)(base - D_INNER) : zr4;
    ushort4 X2 = (l >= 2) ? *(const ushort4*)(base - 2 * D_INNER) : zr4;
    ushort4 X3 = (l >= 3) ? *(const ushort4*)(base - 3 * D_INNER) : zr4;
    float4 bias = *(const float4*)(cb + d4);
    const float4* wv = (const float4*)(cw + (size_t)d4 * 4);
    float xs0[4] = {bf2f(X0.x), bf2f(X0.y), bf2f(X0.z), bf2f(X0.w)};
    float xs1[4] = {bf2f(X1.x), bf2f(X1.y), bf2f(X1.z), bf2f(X1.w)};
    float xs2[4] = {bf2f(X2.x), bf2f(X2.y), bf2f(X2.z), bf2f(X2.w)};
    float xs3[4] = {bf2f(X3.x), bf2f(X3.y), bf2f(X3.z), bf2f(X3.w)};
    float bs[4] = {bias.x, bias.y, bias.z, bias.w};
    ushort4 ob;
    unsigned short* obp = (unsigned short*)&ob;
#pragma unroll
    for (int e = 0; e < 4; ++e) {
        float4 we = wv[e];
        float acc = bs[e];
        acc = fmaf(we.w, xs0[e], acc);
        acc = fmaf(we.z, xs1[e], acc);
        acc = fmaf(we.y, xs2[e], acc);
        acc = fmaf(we.x, xs3[e], acc);
        obp[e] = f2bf(acc / (1.f + __expf(-acc)));
    }
    *(ushort4*)(outb + (size_t)bl * D_INNER + d4) = ob;
}

// ---------------- scan phase 1: per-chunk local scan (h0 = 0) ----------------
__global__ __launch_bounds__(256) void scan_local(const float* __restrict__ xp,
                                                  const unsigned short* __restrict__ delta,
                                                  const unsigned short* __restrict__ ub,
                                                  const float* __restrict__ A_log,
                                                  float* __restrict__ hst,
                                                  float* __restrict__ sdel) {
    int bc = blockIdx.x >> 3;
    int b = bc >> 5, c = bc & (NC - 1);
    int d = (blockIdx.x & 7) * 256 + threadIdx.x;
    int base_r = b * LSEQ + c * CL;
    __shared__ float Bsm[CL * 16];
    for (int e = threadIdx.x; e < CL * 16; e += 256) {
        int l = e >> 4, n = e & 15;
        Bsm[e] = xp[(size_t)(base_r + l) * XPN + DT_RANK + n];
    }
    __syncthreads();
    float Av[16];
    const float4* ap = (const float4*)(A_log + (size_t)d * 16);
#pragma unroll
    for (int qq = 0; qq < 4; ++qq) {
        float4 a = ap[qq];
        Av[4 * qq + 0] = -__expf(a.x); Av[4 * qq + 1] = -__expf(a.y);
        Av[4 * qq + 2] = -__expf(a.z); Av[4 * qq + 3] = -__expf(a.w);
    }
    float h[16] = {};
    float sd = 0.f;
    const unsigned short* dp = delta + (size_t)base_r * D_INNER + d;
    const unsigned short* up = ub + (size_t)base_r * D_INNER + d;
#pragma unroll 4
    for (int l = 0; l < CL; ++l) {
        float dv = bf2f(dp[(size_t)l * D_INNER]);
        float u = bf2f(up[(size_t)l * D_INNER]);
        float du = dv * u;
        sd += dv;
#pragma unroll
        for (int n = 0; n < 16; ++n) {
            float dA = __expf(dv * Av[n]);
            h[n] = fmaf(dA, h[n], du * Bsm[l * 16 + n]);
        }
    }
    size_t hi = ((size_t)(c * NB + b) * D_INNER + d) * 16;
#pragma unroll
    for (int qq = 0; qq < 4; ++qq) {
        float4 v = make_float4(h[4 * qq], h[4 * qq + 1], h[4 * qq + 2], h[4 * qq + 3]);
        *(float4*)(hst + hi + 4 * qq) = v;
    }
    sdel[(size_t)(c * NB + b) * D_INNER + d] = sd;
}

// ---------------- scan phase 2: cross-chunk combine ----------------
__global__ __launch_bounds__(256) void scan_combine(const float* __restrict__ A_log,
                                                    const float* __restrict__ sdel,
                                                    float* __restrict__ hst) {
    int t = blockIdx.x * 256 + threadIdx.x;
    int n = t & 15, d = (t >> 4) & (D_INNER - 1), b = t >> 15;
    float Avn = -__expf(A_log[(size_t)d * 16 + n]);
    float h = 0.f;
#pragma unroll 4
    for (int c = 0; c < NC; ++c) {
        size_t base = (size_t)(c * NB + b) * D_INNER + d;
        float* hp = hst + base * 16 + n;
        float S = sdel[base];
        float tmp = *hp;
        *hp = h;
        h = fmaf(__expf(Avn * S), h, tmp);
    }
}

// ---------------- scan phase 3: finalize, fuse silu(z) gate -> bf16 y ----------------
__global__ __launch_bounds__(256) void scan_final(const float* __restrict__ xp,
                                                  const unsigned short* __restrict__ delta,
                                                  const unsigned short* __restrict__ ub,
                                                  const unsigned short* __restrict__ zb,
                                                  const float* __restrict__ hst,
                                                  const float* __restrict__ A_log,
                                                  const float* __restrict__ Dp,
                                                  unsigned short* __restrict__ yb) {
    int bc = blockIdx.x >> 3;
    int b = bc >> 5, c = bc & (NC - 1);
    int d = (blockIdx.x & 7) * 256 + threadIdx.x;
    int base_r = b * LSEQ + c * CL;
    __shared__ float Bsm[CL * 16], Csm[CL * 16];
    for (int e = threadIdx.x; e < CL * 16; e += 256) {
        int l = e >> 4, n = e & 15;
        Bsm[e] = xp[(size_t)(base_r + l) * XPN + DT_RANK + n];
        Csm[e] = xp[(size_t)(base_r + l) * XPN + DT_RANK + 16 + n];
    }
    __syncthreads();
    float Av[16];
    const float4* ap = (const float4*)(A_log + (size_t)d * 16);
#pragma unroll
    for (int qq = 0; qq < 4; ++qq) {
        float4 a = ap[qq];
        Av[4 * qq + 0] = -__expf(a.x); Av[4 * qq + 1] = -__expf(a.y);
        Av[4 * qq + 2] = -__expf(a.z); Av[4 * qq + 3] = -__expf(a.w);
    }
    float h[16];
    size_t hi = ((size_t)(c * NB + b) * D_INNER + d) * 16;
#pragma unroll
    for (int qq = 0; qq < 4; ++qq) {
        float4 v = *(const float4*)(hst + hi + 4 * qq);
        h[4 * qq] = v.x; h[4 * qq + 1] = v.y; h[4 * qq + 2] = v.z; h[4 * qq + 3] = v.w;
    }
    float Dv = Dp[d];
    const unsigned short* dp = delta + (size_t)base_r * D_INNER + d;
    const unsigned short* up = ub + (size_t)base_r * D_INNER + d;
    const unsigned short* zp = zb + (size_t)base_r * D_INNER + d;
#pragma unroll 4
    for (int l = 0; l < CL; ++l) {
        float dv = bf2f(dp[(size_t)l * D_INNER]);
        float u = bf2f(up[(size_t)l * D_INNER]);
        float du = dv * u;
        float acc = 0.f;
#pragma unroll
        for (int n = 0; n < 16; ++n) {
            float dA = __expf(dv * Av[n]);
            h[n] = fmaf(dA, h[n], du * Bsm[l * 16 + n]);
            acc = fmaf(h[n], Csm[l * 16 + n], acc);
        }
        float yv = fmaf(u, Dv, acc);
        float zv = bf2f(zp[(size_t)l * D_INNER]);
        float sz = zv / (1.f + __expf(-zv));
        yb[(size_t)(base_r + l) * D_INNER + d] = f2bf(yv * sz);
    }
}

extern "C" void kernel_launch(void* const* d_in, const int* in_sizes, int n_in,
                              void* d_out, int out_size, void* d_ws, size_t ws_size,
                              hipStream_t stream) {
    const float* hidden = (const float*)d_in[0];
    const float* norm_w = (const float*)d_in[1];
    const float* norm_b = (const float*)d_in[2];
    const float* in_proj_w = (const float*)d_in[3];
    const float* conv_w = (const float*)d_in[4];
    const float* conv_b = (const float*)d_in[5];
    const float* x_proj_w = (const float*)d_in[6];
    const float* dt_proj_w = (const float*)d_in[7];
    const float* dt_proj_b = (const float*)d_in[8];
    const float* A_log = (const float*)d_in[9];
    const float* D_param = (const float*)d_in[10];
    const float* out_proj_w = (const float*)d_in[11];
    float* out = (float*)d_out;

    float* wsf = (float*)d_ws;
    unsigned short* hbufb = (unsigned short*)wsf;
    float* xpbuf = wsf;
    float* sdelbuf = wsf + 196608;
    unsigned short* xb = (unsigned short*)(wsf + 1048576);
    float* hst = wsf + 1048576;
    unsigned short* zb = (unsigned short*)(wsf + 3145728);
    unsigned short* ub = (unsigned short*)(wsf + 5242880);
    unsigned short* yb = ub;
    unsigned short* wAt = (unsigned short*)(wsf + 7340032);
    float* xpart = wsf + 7340032;
    unsigned short* opart = (unsigned short*)(wsf + 7340032);
    unsigned short* wXt = (unsigned short*)(wsf + 10485760);
    unsigned short* wDt = (unsigned short*)(wsf + 10616832);
    unsigned short* dtrb = (unsigned short*)(wsf + 10682368);
    unsigned short* deltab = (unsigned short*)(wsf + 11665408);
    unsigned short* wOt = (unsigned short*)(wsf + 13762560);

    // 1. all weight casts, one dispatch
    wcast_all<<<6528, 256, 0, stream>>>(in_proj_w, wAt, x_proj_w, wXt, out_proj_w, wOt,
                                        dt_proj_w, wDt);

    // 2. LayerNorm -> bf16
    ln_kernel<<<NROWS, 256, 0, stream>>>(hidden, norm_w, norm_b, hbufb);

    // 3. xz = h @ in_proj_w : x-half bf16 -> xb, z-half bf16 -> zb
    gemm_bf16<2><<<dim3(4096 / 128, NROWS / 128, 1), 256, 0, stream>>>(
        hbufb, wAt, nullptr, (float*)xb, zb, NROWS, 1024, 2048, 4096);

    // 4. conv + silu -> bf16 u
    conv_silu_kernel<<<(NROWS * D_INNER) / 1024, 256, 0, stream>>>(xb, conv_w, conv_b, ub);

    // 5. xp partials = u @ x_proj_w (split-K = 16)
    gemm_bf16<0><<<dim3(1, NROWS / 128, 16), 256, 0, stream>>>(
        ub, wXt, nullptr, xpart, nullptr, NROWS, 2048, XPN, XPN);

    // 6. reduce partials -> xp f32 + dt_r bf16
    reduce_xp<<<(NROWS * XPN) / 256, 256, 0, stream>>>(xpart, xpbuf, dtrb);

    // 6b. delta = softplus(dt_r @ dt_proj_w + b) -> bf16 (MFMA)
    gemm_bf16<4><<<dim3(D_INNER / 128, NROWS / 128, 1), 256, 0, stream>>>(
        dtrb, wDt, dt_proj_b, nullptr, deltab, NROWS, 64, D_INNER, D_INNER);

    // 7-9. chunked selective scan + fused gate -> bf16 y
    scan_local<<<NB * NC * (D_INNER / 256), 256, 0, stream>>>(
        xpbuf, deltab, ub, A_log, hst, sdelbuf);
    scan_combine<<<(NB * D_INNER * D_STATE) / 256, 256, 0, stream>>>(
        A_log, sdelbuf, hst);
    scan_final<<<NB * NC * (D_INNER / 256), 256, 0, stream>>>(
        xpbuf, deltab, ub, zb, hst, A_log, D_param, yb);

    // 10. out partials = y @ out_proj_w (split-K = 4, f16 partials)
    gemm_bf16<3><<<dim3(1024 / 128, NROWS / 128, 4), 256, 0, stream>>>(
        yb, wOt, nullptr, nullptr, opart, NROWS, 2048, 1024, 1024);

    // 11. reduce f16 partials -> d_out
    reduce_out<<<(NROWS * D_MODEL / 4) / 256, 256, 0, stream>>>(opart, out);
}

// Round 10
// 168.027 us; speedup vs baseline: 1.1937x; 1.0776x over previous
//
#include <hip/hip_runtime.h>
#include <hip/hip_bf16.h>

#define D_MODEL 1024
#define D_INNER 2048
#define D_STATE 16
#define DT_RANK 64
#define NB 2
#define LSEQ 1024
#define NROWS (NB * LSEQ)
#define XPN 96
#define NC 32
#define CL 32

typedef __attribute__((ext_vector_type(8))) short bf16x8;
typedef __attribute__((ext_vector_type(4))) float f32x4;

__device__ __forceinline__ unsigned short f2bf(float x) {
    __hip_bfloat16 h = __float2bfloat16(x);
    return *reinterpret_cast<unsigned short*>(&h);
}
__device__ __forceinline__ float bf2f(unsigned short u) {
    unsigned int v = ((unsigned int)u) << 16;
    float f;
    __builtin_memcpy(&f, &v, 4);
    return f;
}
__device__ __forceinline__ unsigned short f2h(float x) {
    _Float16 h = (_Float16)x;
    unsigned short u;
    __builtin_memcpy(&u, &h, 2);
    return u;
}
__device__ __forceinline__ float h2f(unsigned short u) {
    _Float16 h;
    __builtin_memcpy(&h, &u, 2);
    return (float)h;
}

// ---------------- weight casts + LayerNorm in ONE dispatch ----------------
// jobs 0-3: weight cast+transpose (as before); job 4 (bid >= 6528): LN rows.
__global__ __launch_bounds__(256) void wcast_ln(const float* __restrict__ W0, unsigned short* __restrict__ D0,
                                                const float* __restrict__ W1, unsigned short* __restrict__ D1,
                                                const float* __restrict__ W2, unsigned short* __restrict__ D2,
                                                const float* __restrict__ W3, unsigned short* __restrict__ D3,
                                                const float* __restrict__ hx, const float* __restrict__ nw,
                                                const float* __restrict__ nb, unsigned short* __restrict__ lnout) {
    int bid = blockIdx.x;
    if (bid >= 6528) {
        // ---- LayerNorm row ----
        int row = bid - 6528;
        const float4* xr = (const float4*)(hx + (size_t)row * D_MODEL);
        float4 v = xr[threadIdx.x];
        float s = v.x + v.y + v.z + v.w;
        float sq = v.x * v.x + v.y * v.y + v.z * v.z + v.w * v.w;
#pragma unroll
        for (int off = 32; off > 0; off >>= 1) {
            s += __shfl_down(s, off);
            sq += __shfl_down(sq, off);
        }
        __shared__ float ws[4], wq[4];
        __shared__ float smu, srstd;
        int wave = threadIdx.x >> 6;
        if ((threadIdx.x & 63) == 0) { ws[wave] = s; wq[wave] = sq; }
        __syncthreads();
        if (threadIdx.x == 0) {
            float ts = ws[0] + ws[1] + ws[2] + ws[3];
            float tq = wq[0] + wq[1] + wq[2] + wq[3];
            float mu = ts * (1.f / D_MODEL);
            float var = tq * (1.f / D_MODEL) - mu * mu;
            smu = mu;
            srstd = rsqrtf(var + 1e-5f);
        }
        __syncthreads();
        float mu = smu, rstd = srstd;
        float4 wv = ((const float4*)nw)[threadIdx.x];
        float4 bv = ((const float4*)nb)[threadIdx.x];
        ushort4 pk;
        pk.x = f2bf((v.x - mu) * rstd * wv.x + bv.x);
        pk.y = f2bf((v.y - mu) * rstd * wv.y + bv.y);
        pk.z = f2bf((v.z - mu) * rstd * wv.z + bv.z);
        pk.w = f2bf((v.w - mu) * rstd * wv.w + bv.w);
        *(ushort4*)(lnout + (size_t)row * D_MODEL + threadIdx.x * 4) = pk;
        return;
    }
    const float* W;
    unsigned short* Dst;
    int K, Nreal, bx, by;
    if (bid < 4096) { W = W0; Dst = D0; K = 1024; Nreal = 4096; bx = bid & 127; by = bid >> 7; }
    else if (bid < 4352) { int j = bid - 4096; W = W1; Dst = D1; K = 2048; Nreal = 96; bx = j & 3; by = j >> 2; }
    else if (bid < 6400) { int j = bid - 4352; W = W2; Dst = D2; K = 2048; Nreal = 1024; bx = j & 31; by = j >> 5; }
    else { int j = bid - 6400; W = W3; Dst = D3; K = 64; Nreal = 2048; bx = j & 63; by = j >> 6; }
    __shared__ float t[32][33];
    int tn = bx * 32, tk = by * 32;
    for (int e = threadIdx.x; e < 1024; e += 256) {
        int r = e >> 5, c = e & 31;
        int n = tn + c;
        t[r][c] = (n < Nreal) ? W[(size_t)(tk + r) * Nreal + n] : 0.f;
    }
    __syncthreads();
    for (int e = threadIdx.x; e < 1024; e += 256) {
        int r = e >> 5, c = e & 31;
        Dst[(size_t)(tn + r) * K + tk + c] = f2bf(t[c][r]);
    }
}

// ---------------- bf16 MFMA GEMM: C = A[M][K] @ Bt[N][K]^T ----------------
// 128x128 tile, BK=64, 4 waves, global_load_lds with T2 source-pre-swizzle
// (linear LDS dest + XOR'd global src chunk + XOR'd read = identity; kills the
// 16-way bank conflict of stride-128B rows). K must be divisible by 64*gridDim.z.
// EPI 0: f32 C (+split-K zoff). EPI 2: xz-split bf16. EPI 3: f16 partials. EPI 4: softplus->bf16.
template <int EPI>
__global__ __launch_bounds__(256) void gemm_bf16(const unsigned short* __restrict__ A,
                                                 const unsigned short* __restrict__ Bt,
                                                 const float* __restrict__ bias,
                                                 float* __restrict__ C,
                                                 void* __restrict__ C2,
                                                 int M, int K, int ldc, int Nreal) {
    __shared__ unsigned short As[128 * 64];
    __shared__ unsigned short Bs[128 * 64];
    int nwg = gridDim.x * gridDim.y;
    int orig = blockIdx.y * gridDim.x + blockIdx.x;
    int q = nwg >> 3, r = nwg & 7;
    int xcd = orig & 7, idx = orig >> 3;
    int newid = (xcd < r ? xcd * (q + 1) : r * (q + 1) + (xcd - r) * q) + idx;
    int bx = newid % gridDim.x, by = newid / gridDim.x;

    int tid = threadIdx.x;
    int lane = tid & 63;
    int wave = tid >> 6;
    int wr = (wave >> 1) * 64, wc = (wave & 1) * 64;
    int bm = by * 128, bn = bx * 128;
    int kchunk = K / gridDim.z;
    int kbeg = blockIdx.z * kchunk;

    f32x4 acc[4][4];
#pragma unroll
    for (int i = 0; i < 4; ++i)
#pragma unroll
        for (int j = 0; j < 4; ++j) acc[i][j] = (f32x4){0.f, 0.f, 0.f, 0.f};

    // staging map: seg = s*256+tid; row = seg>>3, lds chunk pos p = seg&7;
    // global data chunk c = p ^ (row&7)  (inverse of read-side XOR)
    int ar = lane & 15;
    int kq = lane >> 4;          // quarter-wave: data chunk sub-index

    for (int k0 = kbeg; k0 < kbeg + kchunk; k0 += 64) {
        __syncthreads();
#pragma unroll
        for (int s = 0; s < 4; ++s) {
            int seg = s * 256 + tid;
            int row = seg >> 3, p = seg & 7;
            int c = p ^ (row & 7);
            __builtin_amdgcn_global_load_lds(
                (const __attribute__((address_space(1))) void*)(A + (size_t)(bm + row) * K + k0 + c * 8),
                (__attribute__((address_space(3))) void*)(As + seg * 8), 16, 0, 0);
        }
#pragma unroll
        for (int s = 0; s < 4; ++s) {
            int seg = s * 256 + tid;
            int row = seg >> 3, p = seg & 7;
            int c = p ^ (row & 7);
            __builtin_amdgcn_global_load_lds(
                (const __attribute__((address_space(1))) void*)(Bt + (size_t)(bn + row) * K + k0 + c * 8),
                (__attribute__((address_space(3))) void*)(Bs + seg * 8), 16, 0, 0);
        }
        __syncthreads();
#pragma unroll
        for (int kk = 0; kk < 2; ++kk) {
            bf16x8 af[4], bfr[4];
#pragma unroll
            for (int i = 0; i < 4; ++i) {
                int row = wr + i * 16 + ar;
                int pos = ((kk << 2) | kq) ^ (row & 7);
                af[i] = *(const bf16x8*)&As[(size_t)row * 64 + pos * 8];
            }
#pragma unroll
            for (int j = 0; j < 4; ++j) {
                int row = wc + j * 16 + ar;
                int pos = ((kk << 2) | kq) ^ (row & 7);
                bfr[j] = *(const bf16x8*)&Bs[(size_t)row * 64 + pos * 8];
            }
#pragma unroll
            for (int i = 0; i < 4; ++i)
#pragma unroll
                for (int j = 0; j < 4; ++j)
                    acc[i][j] = __builtin_amdgcn_mfma_f32_16x16x32_bf16(af[i], bfr[j], acc[i][j], 0, 0, 0);
        }
    }

    int crow0 = bm + wr + (lane >> 4) * 4;
    int ccol0 = bn + wc + (lane & 15);
    size_t zoff = (size_t)blockIdx.z * (size_t)M * ldc;
#pragma unroll
    for (int i = 0; i < 4; ++i)
#pragma unroll
        for (int j = 0; j < 4; ++j) {
            int col = ccol0 + j * 16;
            if (EPI == 0) {
                if (col < Nreal) {
                    float* cp = C + zoff + (size_t)(crow0 + i * 16) * ldc + col;
#pragma unroll
                    for (int rr = 0; rr < 4; ++rr) cp[(size_t)rr * ldc] = acc[i][j][rr];
                }
            } else if (EPI == 2) {
                unsigned short* cx = (unsigned short*)C;
                unsigned short* cz = (unsigned short*)C2;
                if (col < 2048) {
#pragma unroll
                    for (int rr = 0; rr < 4; ++rr)
                        cx[(size_t)(crow0 + i * 16 + rr) * 2048 + col] = f2bf(acc[i][j][rr]);
                } else {
#pragma unroll
                    for (int rr = 0; rr < 4; ++rr)
                        cz[(size_t)(crow0 + i * 16 + rr) * 2048 + (col - 2048)] = f2bf(acc[i][j][rr]);
                }
            } else if (EPI == 3) {
                unsigned short* cp = (unsigned short*)C2 + zoff + (size_t)(crow0 + i * 16) * ldc + col;
#pragma unroll
                for (int rr = 0; rr < 4; ++rr) cp[(size_t)rr * ldc] = f2h(acc[i][j][rr]);
            } else {  // EPI == 4
                float bv = bias[col];
                unsigned short* cp = (unsigned short*)C2 + (size_t)(crow0 + i * 16) * ldc + col;
#pragma unroll
                for (int rr = 0; rr < 4; ++rr) {
                    float v = acc[i][j][rr] + bv;
                    v = (v > 20.f) ? v : log1pf(__expf(v));
                    cp[(size_t)rr * ldc] = f2bf(v);
                }
            }
        }
}

// ---------------- split-K reduce for xp (KS=16) + bf16 dt_r extract ----------------
__global__ __launch_bounds__(256) void reduce_xp(const float* __restrict__ part,
                                                 float* __restrict__ xp,
                                                 unsigned short* __restrict__ dtr) {
    int t = blockIdx.x * 256 + threadIdx.x;
    float s = 0.f;
#pragma unroll
    for (int k = 0; k < 16; ++k) s += part[(size_t)k * ((size_t)NROWS * XPN) + t];
    xp[t] = s;
    int row = t / 96, col = t - row * 96;
    if (col < 64) dtr[(size_t)row * 64 + col] = f2bf(s);
}

// ---------------- split-K reduce for out (KS=4, f16 partials) ----------------
__global__ __launch_bounds__(256) void reduce_out(const unsigned short* __restrict__ part,
                                                  float* __restrict__ out) {
    int t = blockIdx.x * 256 + threadIdx.x;
    const size_t stride = (size_t)NROWS * D_MODEL;
    ushort4 p0 = ((const ushort4*)part)[t];
    ushort4 p1 = ((const ushort4*)(part + stride))[t];
    ushort4 p2 = ((const ushort4*)(part + 2 * stride))[t];
    ushort4 p3 = ((const ushort4*)(part + 3 * stride))[t];
    float4 o;
    o.x = h2f(p0.x) + h2f(p1.x) + h2f(p2.x) + h2f(p3.x);
    o.y = h2f(p0.y) + h2f(p1.y) + h2f(p2.y) + h2f(p3.y);
    o.z = h2f(p0.z) + h2f(p1.z) + h2f(p2.z) + h2f(p3.z);
    o.w = h2f(p0.w) + h2f(p1.w) + h2f(p2.w) + h2f(p3.w);
    ((float4*)out)[t] = o;
}

// ---------------- causal depthwise conv (k=4) + SiLU, bf16 in -> bf16 out ----------------
__global__ __launch_bounds__(256) void conv_silu_kernel(const unsigned short* __restrict__ xx,
                                                        const float* __restrict__ cw,
                                                        const float* __restrict__ cb,
                                                        unsigned short* __restrict__ outb) {
    int gid = blockIdx.x * 256 + threadIdx.x;
    int d4 = (gid & 511) << 2;
    int bl = gid >> 9;
    int l = bl & (LSEQ - 1);
    const unsigned short* base = xx + (size_t)bl * D_INNER + d4;
    ushort4 zr4 = {0, 0, 0, 0};
    ushort4 X0 = *(const ushort4*)base;
    ushort4 X1 = (l >= 1) ? *(const ushort4*)(base - D_INNER) : zr4;
    ushort4 X2 = (l >= 2) ? *(const ushort4*)(base - 2 * D_INNER) : zr4;
    ushort4 X3 = (l >= 3) ? *(const ushort4*)(base - 3 * D_INNER) : zr4;
    float4 bias = *(const float4*)(cb + d4);
    const float4* wv = (const float4*)(cw + (size_t)d4 * 4);
    float xs0[4] = {bf2f(X0.x), bf2f(X0.y), bf2f(X0.z), bf2f(X0.w)};
    float xs1[4] = {bf2f(X1.x), bf2f(X1.y), bf2f(X1.z), bf2f(X1.w)};
    float xs2[4] = {bf2f(X2.x), bf2f(X2.y), bf2f(X2.z), bf2f(X2.w)};
    float xs3[4] = {bf2f(X3.x), bf2f(X3.y), bf2f(X3.z), bf2f(X3.w)};
    float bs[4] = {bias.x, bias.y, bias.z, bias.w};
    ushort4 ob;
    unsigned short* obp = (unsigned short*)&ob;
#pragma unroll
    for (int e = 0; e < 4; ++e) {
        float4 we = wv[e];
        float acc = bs[e];
        acc = fmaf(we.w, xs0[e], acc);
        acc = fmaf(we.z, xs1[e], acc);
        acc = fmaf(we.y, xs2[e], acc);
        acc = fmaf(we.x, xs3[e], acc);
        obp[e] = f2bf(acc / (1.f + __expf(-acc)));
    }
    *(ushort4*)(outb + (size_t)bl * D_INNER + d4) = ob;
}

// ---------------- scan phase 1: per-chunk local scan (h0 = 0) ----------------
__global__ __launch_bounds__(256) void scan_local(const float* __restrict__ xp,
                                                  const unsigned short* __restrict__ delta,
                                                  const unsigned short* __restrict__ ub,
                                                  const float* __restrict__ A_log,
                                                  float* __restrict__ hst,
                                                  float* __restrict__ sdel) {
    int bc = blockIdx.x >> 3;
    int b = bc >> 5, c = bc & (NC - 1);
    int d = (blockIdx.x & 7) * 256 + threadIdx.x;
    int base_r = b * LSEQ + c * CL;
    __shared__ float Bsm[CL * 16];
    for (int e = threadIdx.x; e < CL * 16; e += 256) {
        int l = e >> 4, n = e & 15;
        Bsm[e] = xp[(size_t)(base_r + l) * XPN + DT_RANK + n];
    }
    __syncthreads();
    float Av[16];
    const float4* ap = (const float4*)(A_log + (size_t)d * 16);
#pragma unroll
    for (int qq = 0; qq < 4; ++qq) {
        float4 a = ap[qq];
        Av[4 * qq + 0] = -__expf(a.x); Av[4 * qq + 1] = -__expf(a.y);
        Av[4 * qq + 2] = -__expf(a.z); Av[4 * qq + 3] = -__expf(a.w);
    }
    float h[16] = {};
    float sd = 0.f;
    const unsigned short* dp = delta + (size_t)base_r * D_INNER + d;
    const unsigned short* up = ub + (size_t)base_r * D_INNER + d;
#pragma unroll 4
    for (int l = 0; l < CL; ++l) {
        float dv = bf2f(dp[(size_t)l * D_INNER]);
        float u = bf2f(up[(size_t)l * D_INNER]);
        float du = dv * u;
        sd += dv;
#pragma unroll
        for (int n = 0; n < 16; ++n) {
            float dA = __expf(dv * Av[n]);
            h[n] = fmaf(dA, h[n], du * Bsm[l * 16 + n]);
        }
    }
    size_t hi = ((size_t)(c * NB + b) * D_INNER + d) * 16;
#pragma unroll
    for (int qq = 0; qq < 4; ++qq) {
        float4 v = make_float4(h[4 * qq], h[4 * qq + 1], h[4 * qq + 2], h[4 * qq + 3]);
        *(float4*)(hst + hi + 4 * qq) = v;
    }
    sdel[(size_t)(c * NB + b) * D_INNER + d] = sd;
}

// ---------------- scan phase 2: cross-chunk combine ----------------
__global__ __launch_bounds__(256) void scan_combine(const float* __restrict__ A_log,
                                                    const float* __restrict__ sdel,
                                                    float* __restrict__ hst) {
    int t = blockIdx.x * 256 + threadIdx.x;
    int n = t & 15, d = (t >> 4) & (D_INNER - 1), b = t >> 15;
    float Avn = -__expf(A_log[(size_t)d * 16 + n]);
    float h = 0.f;
#pragma unroll 4
    for (int c = 0; c < NC; ++c) {
        size_t base = (size_t)(c * NB + b) * D_INNER + d;
        float* hp = hst + base * 16 + n;
        float S = sdel[base];
        float tmp = *hp;
        *hp = h;
        h = fmaf(__expf(Avn * S), h, tmp);
    }
}

// ---------------- scan phase 3: finalize, fuse silu(z) gate -> bf16 y ----------------
__global__ __launch_bounds__(256) void scan_final(const float* __restrict__ xp,
                                                  const unsigned short* __restrict__ delta,
                                                  const unsigned short* __restrict__ ub,
                                                  const unsigned short* __restrict__ zb,
                                                  const float* __restrict__ hst,
                                                  const float* __restrict__ A_log,
                                                  const float* __restrict__ Dp,
                                                  unsigned short* __restrict__ yb) {
    int bc = blockIdx.x >> 3;
    int b = bc >> 5, c = bc & (NC - 1);
    int d = (blockIdx.x & 7) * 256 + threadIdx.x;
    int base_r = b * LSEQ + c * CL;
    __shared__ float Bsm[CL * 16], Csm[CL * 16];
    for (int e = threadIdx.x; e < CL * 16; e += 256) {
        int l = e >> 4, n = e & 15;
        Bsm[e] = xp[(size_t)(base_r + l) * XPN + DT_RANK + n];
        Csm[e] = xp[(size_t)(base_r + l) * XPN + DT_RANK + 16 + n];
    }
    __syncthreads();
    float Av[16];
    const float4* ap = (const float4*)(A_log + (size_t)d * 16);
#pragma unroll
    for (int qq = 0; qq < 4; ++qq) {
        float4 a = ap[qq];
        Av[4 * qq + 0] = -__expf(a.x); Av[4 * qq + 1] = -__expf(a.y);
        Av[4 * qq + 2] = -__expf(a.z); Av[4 * qq + 3] = -__expf(a.w);
    }
    float h[16];
    size_t hi = ((size_t)(c * NB + b) * D_INNER + d) * 16;
#pragma unroll
    for (int qq = 0; qq < 4; ++qq) {
        float4 v = *(const float4*)(hst + hi + 4 * qq);
        h[4 * qq] = v.x; h[4 * qq + 1] = v.y; h[4 * qq + 2] = v.z; h[4 * qq + 3] = v.w;
    }
    float Dv = Dp[d];
    const unsigned short* dp = delta + (size_t)base_r * D_INNER + d;
    const unsigned short* up = ub + (size_t)base_r * D_INNER + d;
    const unsigned short* zp = zb + (size_t)base_r * D_INNER + d;
#pragma unroll 4
    for (int l = 0; l < CL; ++l) {
        float dv = bf2f(dp[(size_t)l * D_INNER]);
        float u = bf2f(up[(size_t)l * D_INNER]);
        float du = dv * u;
        float acc = 0.f;
#pragma unroll
        for (int n = 0; n < 16; ++n) {
            float dA = __expf(dv * Av[n]);
            h[n] = fmaf(dA, h[n], du * Bsm[l * 16 + n]);
            acc = fmaf(h[n], Csm[l * 16 + n], acc);
        }
        float yv = fmaf(u, Dv, acc);
        float zv = bf2f(zp[(size_t)l * D_INNER]);
        float sz = zv / (1.f + __expf(-zv));
        yb[(size_t)(base_r + l) * D_INNER + d] = f2bf(yv * sz);
    }
}

extern "C" void kernel_launch(void* const* d_in, const int* in_sizes, int n_in,
                              void* d_out, int out_size, void* d_ws, size_t ws_size,
                              hipStream_t stream) {
    const float* hidden = (const float*)d_in[0];
    const float* norm_w = (const float*)d_in[1];
    const float* norm_b = (const float*)d_in[2];
    const float* in_proj_w = (const float*)d_in[3];
    const float* conv_w = (const float*)d_in[4];
    const float* conv_b = (const float*)d_in[5];
    const float* x_proj_w = (const float*)d_in[6];
    const float* dt_proj_w = (const float*)d_in[7];
    const float* dt_proj_b = (const float*)d_in[8];
    const float* A_log = (const float*)d_in[9];
    const float* D_param = (const float*)d_in[10];
    const float* out_proj_w = (const float*)d_in[11];
    float* out = (float*)d_out;

    float* wsf = (float*)d_ws;
    unsigned short* hbufb = (unsigned short*)wsf;
    float* xpbuf = wsf;
    float* sdelbuf = wsf + 196608;
    unsigned short* xb = (unsigned short*)(wsf + 1048576);
    float* hst = wsf + 1048576;
    unsigned short* zb = (unsigned short*)(wsf + 3145728);
    unsigned short* ub = (unsigned short*)(wsf + 5242880);
    unsigned short* yb = ub;
    unsigned short* wAt = (unsigned short*)(wsf + 7340032);
    float* xpart = wsf + 7340032;
    unsigned short* opart = (unsigned short*)(wsf + 7340032);
    unsigned short* wXt = (unsigned short*)(wsf + 10485760);
    unsigned short* wDt = (unsigned short*)(wsf + 10616832);
    unsigned short* dtrb = (unsigned short*)(wsf + 10682368);
    unsigned short* deltab = (unsigned short*)(wsf + 11665408);
    unsigned short* wOt = (unsigned short*)(wsf + 13762560);

    // 1. all weight casts + LayerNorm, one dispatch
    wcast_ln<<<6528 + NROWS, 256, 0, stream>>>(in_proj_w, wAt, x_proj_w, wXt, out_proj_w, wOt,
                                               dt_proj_w, wDt, hidden, norm_w, norm_b, hbufb);

    // 2. xz = h @ in_proj_w : x-half bf16 -> xb, z-half bf16 -> zb
    gemm_bf16<2><<<dim3(4096 / 128, NROWS / 128, 1), 256, 0, stream>>>(
        hbufb, wAt, nullptr, (float*)xb, zb, NROWS, 1024, 2048, 4096);

    // 3. conv + silu -> bf16 u
    conv_silu_kernel<<<(NROWS * D_INNER) / 1024, 256, 0, stream>>>(xb, conv_w, conv_b, ub);

    // 4. xp partials = u @ x_proj_w (split-K = 16, 128 cols of K each)
    gemm_bf16<0><<<dim3(1, NROWS / 128, 16), 256, 0, stream>>>(
        ub, wXt, nullptr, xpart, nullptr, NROWS, 2048, XPN, XPN);

    // 5. reduce partials -> xp f32 + dt_r bf16
    reduce_xp<<<(NROWS * XPN) / 256, 256, 0, stream>>>(xpart, xpbuf, dtrb);

    // 6. delta = softplus(dt_r @ dt_proj_w + b) -> bf16 (MFMA, K=64 = one BK step)
    gemm_bf16<4><<<dim3(D_INNER / 128, NROWS / 128, 1), 256, 0, stream>>>(
        dtrb, wDt, dt_proj_b, nullptr, deltab, NROWS, 64, D_INNER, D_INNER);

    // 7-9. chunked selective scan + fused gate -> bf16 y
    scan_local<<<NB * NC * (D_INNER / 256), 256, 0, stream>>>(
        xpbuf, deltab, ub, A_log, hst, sdelbuf);
    scan_combine<<<(NB * D_INNER * D_STATE) / 256, 256, 0, stream>>>(
        A_log, sdelbuf, hst);
    scan_final<<<NB * NC * (D_INNER / 256), 256, 0, stream>>>(
        xpbuf, deltab, ub, zb, hst, A_log, D_param, yb);

    // 10. out partials = y @ out_proj_w (split-K = 4, f16 partials)
    gemm_bf16<3><<<dim3(1024 / 128, NROWS / 128, 4), 256, 0, stream>>>(
        yb, wOt, nullptr, nullptr, opart, NROWS, 2048, 1024, 1024);

    // 11. reduce f16 partials -> d_out
    reduce_out<<<(NROWS * D_MODEL / 4) / 256, 256, 0, stream>>>(opart, out);
}

// Round 11
// 166.857 us; speedup vs baseline: 1.2021x; 1.0070x over previous
//
#include <hip/hip_runtime.h>
#include <hip/hip_bf16.h>

#define D_MODEL 1024
#define D_INNER 2048
#define D_STATE 16
#define DT_RANK 64
#define NB 2
#define LSEQ 1024
#define NROWS (NB * LSEQ)
#define XPN 96
#define NC 32
#define CL 32

typedef __attribute__((ext_vector_type(8))) short bf16x8;
typedef __attribute__((ext_vector_type(4))) float f32x4;

__device__ __forceinline__ unsigned short f2bf(float x) {
    __hip_bfloat16 h = __float2bfloat16(x);
    return *reinterpret_cast<unsigned short*>(&h);
}
__device__ __forceinline__ float bf2f(unsigned short u) {
    unsigned int v = ((unsigned int)u) << 16;
    float f;
    __builtin_memcpy(&f, &v, 4);
    return f;
}
__device__ __forceinline__ unsigned short f2h(float x) {
    _Float16 h = (_Float16)x;
    unsigned short u;
    __builtin_memcpy(&u, &h, 2);
    return u;
}
__device__ __forceinline__ float h2f(unsigned short u) {
    _Float16 h;
    __builtin_memcpy(&h, &u, 2);
    return (float)h;
}

// ---------------- weight casts + LayerNorm in ONE dispatch ----------------
__global__ __launch_bounds__(256) void wcast_ln(const float* __restrict__ W0, unsigned short* __restrict__ D0,
                                                const float* __restrict__ W1, unsigned short* __restrict__ D1,
                                                const float* __restrict__ W2, unsigned short* __restrict__ D2,
                                                const float* __restrict__ W3, unsigned short* __restrict__ D3,
                                                const float* __restrict__ hx, const float* __restrict__ nw,
                                                const float* __restrict__ nb, unsigned short* __restrict__ lnout) {
    int bid = blockIdx.x;
    if (bid >= 6528) {
        int row = bid - 6528;
        const float4* xr = (const float4*)(hx + (size_t)row * D_MODEL);
        float4 v = xr[threadIdx.x];
        float s = v.x + v.y + v.z + v.w;
        float sq = v.x * v.x + v.y * v.y + v.z * v.z + v.w * v.w;
#pragma unroll
        for (int off = 32; off > 0; off >>= 1) {
            s += __shfl_down(s, off);
            sq += __shfl_down(sq, off);
        }
        __shared__ float ws[4], wq[4];
        __shared__ float smu, srstd;
        int wave = threadIdx.x >> 6;
        if ((threadIdx.x & 63) == 0) { ws[wave] = s; wq[wave] = sq; }
        __syncthreads();
        if (threadIdx.x == 0) {
            float ts = ws[0] + ws[1] + ws[2] + ws[3];
            float tq = wq[0] + wq[1] + wq[2] + wq[3];
            float mu = ts * (1.f / D_MODEL);
            float var = tq * (1.f / D_MODEL) - mu * mu;
            smu = mu;
            srstd = rsqrtf(var + 1e-5f);
        }
        __syncthreads();
        float mu = smu, rstd = srstd;
        float4 wv = ((const float4*)nw)[threadIdx.x];
        float4 bv = ((const float4*)nb)[threadIdx.x];
        ushort4 pk;
        pk.x = f2bf((v.x - mu) * rstd * wv.x + bv.x);
        pk.y = f2bf((v.y - mu) * rstd * wv.y + bv.y);
        pk.z = f2bf((v.z - mu) * rstd * wv.z + bv.z);
        pk.w = f2bf((v.w - mu) * rstd * wv.w + bv.w);
        *(ushort4*)(lnout + (size_t)row * D_MODEL + threadIdx.x * 4) = pk;
        return;
    }
    const float* W;
    unsigned short* Dst;
    int K, Nreal, bx, by;
    if (bid < 4096) { W = W0; Dst = D0; K = 1024; Nreal = 4096; bx = bid & 127; by = bid >> 7; }
    else if (bid < 4352) { int j = bid - 4096; W = W1; Dst = D1; K = 2048; Nreal = 96; bx = j & 3; by = j >> 2; }
    else if (bid < 6400) { int j = bid - 4352; W = W2; Dst = D2; K = 2048; Nreal = 1024; bx = j & 31; by = j >> 5; }
    else { int j = bid - 6400; W = W3; Dst = D3; K = 64; Nreal = 2048; bx = j & 63; by = j >> 6; }
    __shared__ float t[32][33];
    int tn = bx * 32, tk = by * 32;
    for (int e = threadIdx.x; e < 1024; e += 256) {
        int r = e >> 5, c = e & 31;
        int n = tn + c;
        t[r][c] = (n < Nreal) ? W[(size_t)(tk + r) * Nreal + n] : 0.f;
    }
    __syncthreads();
    for (int e = threadIdx.x; e < 1024; e += 256) {
        int r = e >> 5, c = e & 31;
        Dst[(size_t)(tn + r) * K + tk + c] = f2bf(t[c][r]);
    }
}

// ---------------- bf16 MFMA GEMM: C = A[M][K] @ Bt[N][K]^T ----------------
// 128x128 tile, BK=64, T2 source-pre-swizzle, XCD-bijective block swizzle.
// EPI 0: f32 C (+split-K zoff). EPI 2: xz-split bf16. EPI 3: f16 partials (+zoff, Nreal guard).
// EPI 4: softplus(v+bias[col]) -> bf16 C2.
template <int EPI>
__global__ __launch_bounds__(256) void gemm_bf16(const unsigned short* __restrict__ A,
                                                 const unsigned short* __restrict__ Bt,
                                                 const float* __restrict__ bias,
                                                 float* __restrict__ C,
                                                 void* __restrict__ C2,
                                                 int M, int K, int ldc, int Nreal) {
    __shared__ unsigned short As[128 * 64];
    __shared__ unsigned short Bs[128 * 64];
    int nwg = gridDim.x * gridDim.y;
    int orig = blockIdx.y * gridDim.x + blockIdx.x;
    int q = nwg >> 3, r = nwg & 7;
    int xcd = orig & 7, idx = orig >> 3;
    int newid = (xcd < r ? xcd * (q + 1) : r * (q + 1) + (xcd - r) * q) + idx;
    int bx = newid % gridDim.x, by = newid / gridDim.x;

    int tid = threadIdx.x;
    int lane = tid & 63;
    int wave = tid >> 6;
    int wr = (wave >> 1) * 64, wc = (wave & 1) * 64;
    int bm = by * 128, bn = bx * 128;
    int kchunk = K / gridDim.z;
    int kbeg = blockIdx.z * kchunk;

    f32x4 acc[4][4];
#pragma unroll
    for (int i = 0; i < 4; ++i)
#pragma unroll
        for (int j = 0; j < 4; ++j) acc[i][j] = (f32x4){0.f, 0.f, 0.f, 0.f};

    int ar = lane & 15;
    int kq = lane >> 4;

    for (int k0 = kbeg; k0 < kbeg + kchunk; k0 += 64) {
        __syncthreads();
#pragma unroll
        for (int s = 0; s < 4; ++s) {
            int seg = s * 256 + tid;
            int row = seg >> 3, p = seg & 7;
            int c = p ^ (row & 7);
            __builtin_amdgcn_global_load_lds(
                (const __attribute__((address_space(1))) void*)(A + (size_t)(bm + row) * K + k0 + c * 8),
                (__attribute__((address_space(3))) void*)(As + seg * 8), 16, 0, 0);
        }
#pragma unroll
        for (int s = 0; s < 4; ++s) {
            int seg = s * 256 + tid;
            int row = seg >> 3, p = seg & 7;
            int c = p ^ (row & 7);
            __builtin_amdgcn_global_load_lds(
                (const __attribute__((address_space(1))) void*)(Bt + (size_t)(bn + row) * K + k0 + c * 8),
                (__attribute__((address_space(3))) void*)(Bs + seg * 8), 16, 0, 0);
        }
        __syncthreads();
#pragma unroll
        for (int kk = 0; kk < 2; ++kk) {
            bf16x8 af[4], bfr[4];
#pragma unroll
            for (int i = 0; i < 4; ++i) {
                int row = wr + i * 16 + ar;
                int pos = ((kk << 2) | kq) ^ (row & 7);
                af[i] = *(const bf16x8*)&As[(size_t)row * 64 + pos * 8];
            }
#pragma unroll
            for (int j = 0; j < 4; ++j) {
                int row = wc + j * 16 + ar;
                int pos = ((kk << 2) | kq) ^ (row & 7);
                bfr[j] = *(const bf16x8*)&Bs[(size_t)row * 64 + pos * 8];
            }
#pragma unroll
            for (int i = 0; i < 4; ++i)
#pragma unroll
                for (int j = 0; j < 4; ++j)
                    acc[i][j] = __builtin_amdgcn_mfma_f32_16x16x32_bf16(af[i], bfr[j], acc[i][j], 0, 0, 0);
        }
    }

    int crow0 = bm + wr + (lane >> 4) * 4;
    int ccol0 = bn + wc + (lane & 15);
    size_t zoff = (size_t)blockIdx.z * (size_t)M * ldc;
#pragma unroll
    for (int i = 0; i < 4; ++i)
#pragma unroll
        for (int j = 0; j < 4; ++j) {
            int col = ccol0 + j * 16;
            if (EPI == 0) {
                if (col < Nreal) {
                    float* cp = C + zoff + (size_t)(crow0 + i * 16) * ldc + col;
#pragma unroll
                    for (int rr = 0; rr < 4; ++rr) cp[(size_t)rr * ldc] = acc[i][j][rr];
                }
            } else if (EPI == 2) {
                unsigned short* cx = (unsigned short*)C;
                unsigned short* cz = (unsigned short*)C2;
                if (col < 2048) {
#pragma unroll
                    for (int rr = 0; rr < 4; ++rr)
                        cx[(size_t)(crow0 + i * 16 + rr) * 2048 + col] = f2bf(acc[i][j][rr]);
                } else {
#pragma unroll
                    for (int rr = 0; rr < 4; ++rr)
                        cz[(size_t)(crow0 + i * 16 + rr) * 2048 + (col - 2048)] = f2bf(acc[i][j][rr]);
                }
            } else if (EPI == 3) {
                if (col < Nreal) {
                    unsigned short* cp = (unsigned short*)C2 + zoff + (size_t)(crow0 + i * 16) * ldc + col;
#pragma unroll
                    for (int rr = 0; rr < 4; ++rr) cp[(size_t)rr * ldc] = f2h(acc[i][j][rr]);
                }
            } else {  // EPI == 4
                float bv = bias[col];
                unsigned short* cp = (unsigned short*)C2 + (size_t)(crow0 + i * 16) * ldc + col;
#pragma unroll
                for (int rr = 0; rr < 4; ++rr) {
                    float v = acc[i][j][rr] + bv;
                    v = (v > 20.f) ? v : log1pf(__expf(v));
                    cp[(size_t)rr * ldc] = f2bf(v);
                }
            }
        }
}

// ---------------- split-K reduce for xp (KS=16, f16 partials) + bf16 dt_r ----------------
__global__ __launch_bounds__(256) void reduce_xp(const unsigned short* __restrict__ part,
                                                 float* __restrict__ xp,
                                                 unsigned short* __restrict__ dtr) {
    int t = blockIdx.x * 256 + threadIdx.x;
    float s = 0.f;
#pragma unroll
    for (int k = 0; k < 16; ++k) s += h2f(part[(size_t)k * ((size_t)NROWS * XPN) + t]);
    xp[t] = s;
    int row = t / 96, col = t - row * 96;
    if (col < 64) dtr[(size_t)row * 64 + col] = f2bf(s);
}

// ---------------- split-K reduce for out (KS=4, f16 partials) ----------------
__global__ __launch_bounds__(256) void reduce_out(const unsigned short* __restrict__ part,
                                                  float* __restrict__ out) {
    int t = blockIdx.x * 256 + threadIdx.x;
    const size_t stride = (size_t)NROWS * D_MODEL;
    ushort4 p0 = ((const ushort4*)part)[t];
    ushort4 p1 = ((const ushort4*)(part + stride))[t];
    ushort4 p2 = ((const ushort4*)(part + 2 * stride))[t];
    ushort4 p3 = ((const ushort4*)(part + 3 * stride))[t];
    float4 o;
    o.x = h2f(p0.x) + h2f(p1.x) + h2f(p2.x) + h2f(p3.x);
    o.y = h2f(p0.y) + h2f(p1.y) + h2f(p2.y) + h2f(p3.y);
    o.z = h2f(p0.z) + h2f(p1.z) + h2f(p2.z) + h2f(p3.z);
    o.w = h2f(p0.w) + h2f(p1.w) + h2f(p2.w) + h2f(p3.w);
    ((float4*)out)[t] = o;
}

// ---------------- causal depthwise conv (k=4) + SiLU, bf16 in -> bf16 out ----------------
__global__ __launch_bounds__(256) void conv_silu_kernel(const unsigned short* __restrict__ xx,
                                                        const float* __restrict__ cw,
                                                        const float* __restrict__ cb,
                                                        unsigned short* __restrict__ outb) {
    int gid = blockIdx.x * 256 + threadIdx.x;
    int d4 = (gid & 511) << 2;
    int bl = gid >> 9;
    int l = bl & (LSEQ - 1);
    const unsigned short* base = xx + (size_t)bl * D_INNER + d4;
    ushort4 zr4 = {0, 0, 0, 0};
    ushort4 X0 = *(const ushort4*)base;
    ushort4 X1 = (l >= 1) ? *(const ushort4*)(base - D_INNER) : zr4;
    ushort4 X2 = (l >= 2) ? *(const ushort4*)(base - 2 * D_INNER) : zr4;
    ushort4 X3 = (l >= 3) ? *(const ushort4*)(base - 3 * D_INNER) : zr4;
    float4 bias = *(const float4*)(cb + d4);
    const float4* wv = (const float4*)(cw + (size_t)d4 * 4);
    float xs0[4] = {bf2f(X0.x), bf2f(X0.y), bf2f(X0.z), bf2f(X0.w)};
    float xs1[4] = {bf2f(X1.x), bf2f(X1.y), bf2f(X1.z), bf2f(X1.w)};
    float xs2[4] = {bf2f(X2.x), bf2f(X2.y), bf2f(X2.z), bf2f(X2.w)};
    float xs3[4] = {bf2f(X3.x), bf2f(X3.y), bf2f(X3.z), bf2f(X3.w)};
    float bs[4] = {bias.x, bias.y, bias.z, bias.w};
    ushort4 ob;
    unsigned short* obp = (unsigned short*)&ob;
#pragma unroll
    for (int e = 0; e < 4; ++e) {
        float4 we = wv[e];
        float acc = bs[e];
        acc = fmaf(we.w, xs0[e], acc);
        acc = fmaf(we.z, xs1[e], acc);
        acc = fmaf(we.y, xs2[e], acc);
        acc = fmaf(we.x, xs3[e], acc);
        obp[e] = f2bf(acc / (1.f + __expf(-acc)));
    }
    *(ushort4*)(outb + (size_t)bl * D_INNER + d4) = ob;
}

// ---------------- scan phase 1: per-chunk local scan (h0 = 0) ----------------
__global__ __launch_bounds__(256) void scan_local(const float* __restrict__ xp,
                                                  const unsigned short* __restrict__ delta,
                                                  const unsigned short* __restrict__ ub,
                                                  const float* __restrict__ A_log,
                                                  float* __restrict__ hst,
                                                  float* __restrict__ sdel) {
    int bc = blockIdx.x >> 3;
    int b = bc >> 5, c = bc & (NC - 1);
    int d = (blockIdx.x & 7) * 256 + threadIdx.x;
    int base_r = b * LSEQ + c * CL;
    __shared__ float Bsm[CL * 16];
    for (int e = threadIdx.x; e < CL * 4; e += 256) {
        int l = e >> 2, q4 = e & 3;
        float4 v = *(const float4*)&xp[(size_t)(base_r + l) * XPN + DT_RANK + q4 * 4];
        *(float4*)&Bsm[l * 16 + q4 * 4] = v;
    }
    __syncthreads();
    float Av[16];
    const float4* ap = (const float4*)(A_log + (size_t)d * 16);
#pragma unroll
    for (int qq = 0; qq < 4; ++qq) {
        float4 a = ap[qq];
        Av[4 * qq + 0] = -__expf(a.x); Av[4 * qq + 1] = -__expf(a.y);
        Av[4 * qq + 2] = -__expf(a.z); Av[4 * qq + 3] = -__expf(a.w);
    }
    float h[16] = {};
    float sd = 0.f;
    const unsigned short* dp = delta + (size_t)base_r * D_INNER + d;
    const unsigned short* up = ub + (size_t)base_r * D_INNER + d;
#pragma unroll 4
    for (int l = 0; l < CL; ++l) {
        float dv = bf2f(dp[(size_t)l * D_INNER]);
        float u = bf2f(up[(size_t)l * D_INNER]);
        float du = dv * u;
        sd += dv;
#pragma unroll
        for (int n = 0; n < 16; ++n) {
            float dA = __expf(dv * Av[n]);
            h[n] = fmaf(dA, h[n], du * Bsm[l * 16 + n]);
        }
    }
    size_t hi = ((size_t)(c * NB + b) * D_INNER + d) * 16;
#pragma unroll
    for (int qq = 0; qq < 4; ++qq) {
        float4 v = make_float4(h[4 * qq], h[4 * qq + 1], h[4 * qq + 2], h[4 * qq + 3]);
        *(float4*)(hst + hi + 4 * qq) = v;
    }
    sdel[(size_t)(c * NB + b) * D_INNER + d] = sd;
}

// ---------------- scan phase 2: cross-chunk combine (LDS-staged walk) ----------------
// 256 blocks; block covers one b and 16 d's (all 16 n). All 32 chunks staged in LDS,
// walk is in-LDS (no dependent global round-trips), coalesced load/store.
__global__ __launch_bounds__(256) void scan_combine(const float* __restrict__ A_log,
                                                    const float* __restrict__ sdel,
                                                    float* __restrict__ hst) {
    __shared__ float hl[NC][256];
    __shared__ float sl[NC][16];
    int b = blockIdx.x >> 7;
    int d0 = (blockIdx.x & 127) * 16;
    int t = threadIdx.x;
    int dd = t >> 4;
    for (int e = t; e < NC * 256; e += 256) {
        int c = e >> 8, tt = e & 255;
        hl[c][tt] = hst[(size_t)(c * NB + b) * (D_INNER * 16) + d0 * 16 + tt];
    }
    for (int e = t; e < NC * 16; e += 256) {
        int c = e >> 4, ddd = e & 15;
        sl[c][ddd] = sdel[(size_t)(c * NB + b) * D_INNER + d0 + ddd];
    }
    __syncthreads();
    float Avn = -__expf(A_log[(size_t)d0 * 16 + t]);
    float h = 0.f;
#pragma unroll
    for (int c = 0; c < NC; ++c) {
        float S = sl[c][dd];
        float tmp = hl[c][t];
        hl[c][t] = h;
        h = fmaf(__expf(Avn * S), h, tmp);
    }
    __syncthreads();
    for (int e = t; e < NC * 256; e += 256) {
        int c = e >> 8, tt = e & 255;
        hst[(size_t)(c * NB + b) * (D_INNER * 16) + d0 * 16 + tt] = hl[c][tt];
    }
}

// ---------------- scan phase 3: finalize, fuse silu(z) gate -> bf16 y ----------------
__global__ __launch_bounds__(256) void scan_final(const float* __restrict__ xp,
                                                  const unsigned short* __restrict__ delta,
                                                  const unsigned short* __restrict__ ub,
                                                  const unsigned short* __restrict__ zb,
                                                  const float* __restrict__ hst,
                                                  const float* __restrict__ A_log,
                                                  const float* __restrict__ Dp,
                                                  unsigned short* __restrict__ yb) {
    int bc = blockIdx.x >> 3;
    int b = bc >> 5, c = bc & (NC - 1);
    int d = (blockIdx.x & 7) * 256 + threadIdx.x;
    int base_r = b * LSEQ + c * CL;
    __shared__ float Bsm[CL * 16], Csm[CL * 16];
    for (int e = threadIdx.x; e < CL * 8; e += 256) {
        int l = e >> 3, q8 = e & 7;
        float4 v = *(const float4*)&xp[(size_t)(base_r + l) * XPN + DT_RANK + q8 * 4];
        if (q8 < 4) *(float4*)&Bsm[l * 16 + q8 * 4] = v;
        else *(float4*)&Csm[l * 16 + (q8 - 4) * 4] = v;
    }
    __syncthreads();
    float Av[16];
    const float4* ap = (const float4*)(A_log + (size_t)d * 16);
#pragma unroll
    for (int qq = 0; qq < 4; ++qq) {
        float4 a = ap[qq];
        Av[4 * qq + 0] = -__expf(a.x); Av[4 * qq + 1] = -__expf(a.y);
        Av[4 * qq + 2] = -__expf(a.z); Av[4 * qq + 3] = -__expf(a.w);
    }
    float h[16];
    size_t hi = ((size_t)(c * NB + b) * D_INNER + d) * 16;
#pragma unroll
    for (int qq = 0; qq < 4; ++qq) {
        float4 v = *(const float4*)(hst + hi + 4 * qq);
        h[4 * qq] = v.x; h[4 * qq + 1] = v.y; h[4 * qq + 2] = v.z; h[4 * qq + 3] = v.w;
    }
    float Dv = Dp[d];
    const unsigned short* dp = delta + (size_t)base_r * D_INNER + d;
    const unsigned short* up = ub + (size_t)base_r * D_INNER + d;
    const unsigned short* zp = zb + (size_t)base_r * D_INNER + d;
#pragma unroll 4
    for (int l = 0; l < CL; ++l) {
        float dv = bf2f(dp[(size_t)l * D_INNER]);
        float u = bf2f(up[(size_t)l * D_INNER]);
        float du = dv * u;
        float acc = 0.f;
#pragma unroll
        for (int n = 0; n < 16; ++n) {
            float dA = __expf(dv * Av[n]);
            h[n] = fmaf(dA, h[n], du * Bsm[l * 16 + n]);
            acc = fmaf(h[n], Csm[l * 16 + n], acc);
        }
        float yv = fmaf(u, Dv, acc);
        float zv = bf2f(zp[(size_t)l * D_INNER]);
        float sz = zv / (1.f + __expf(-zv));
        yb[(size_t)(base_r + l) * D_INNER + d] = f2bf(yv * sz);
    }
}

extern "C" void kernel_launch(void* const* d_in, const int* in_sizes, int n_in,
                              void* d_out, int out_size, void* d_ws, size_t ws_size,
                              hipStream_t stream) {
    const float* hidden = (const float*)d_in[0];
    const float* norm_w = (const float*)d_in[1];
    const float* norm_b = (const float*)d_in[2];
    const float* in_proj_w = (const float*)d_in[3];
    const float* conv_w = (const float*)d_in[4];
    const float* conv_b = (const float*)d_in[5];
    const float* x_proj_w = (const float*)d_in[6];
    const float* dt_proj_w = (const float*)d_in[7];
    const float* dt_proj_b = (const float*)d_in[8];
    const float* A_log = (const float*)d_in[9];
    const float* D_param = (const float*)d_in[10];
    const float* out_proj_w = (const float*)d_in[11];
    float* out = (float*)d_out;

    float* wsf = (float*)d_ws;
    unsigned short* hbufb = (unsigned short*)wsf;
    float* xpbuf = wsf;
    float* sdelbuf = wsf + 196608;
    unsigned short* xb = (unsigned short*)(wsf + 1048576);
    float* hst = wsf + 1048576;
    unsigned short* zb = (unsigned short*)(wsf + 3145728);
    unsigned short* ub = (unsigned short*)(wsf + 5242880);
    unsigned short* yb = ub;
    unsigned short* wAt = (unsigned short*)(wsf + 7340032);
    unsigned short* xpart16 = (unsigned short*)(wsf + 7340032);   // f16 partials [16][2048][96]
    unsigned short* opart = (unsigned short*)(wsf + 7340032);     // f16 partials [4][2048][1024]
    unsigned short* wXt = (unsigned short*)(wsf + 10485760);
    unsigned short* wDt = (unsigned short*)(wsf + 10616832);
    unsigned short* dtrb = (unsigned short*)(wsf + 10682368);
    unsigned short* deltab = (unsigned short*)(wsf + 11665408);
    unsigned short* wOt = (unsigned short*)(wsf + 13762560);

    // 1. all weight casts + LayerNorm, one dispatch
    wcast_ln<<<6528 + NROWS, 256, 0, stream>>>(in_proj_w, wAt, x_proj_w, wXt, out_proj_w, wOt,
                                               dt_proj_w, wDt, hidden, norm_w, norm_b, hbufb);

    // 2. xz = h @ in_proj_w : x-half bf16 -> xb, z-half bf16 -> zb
    gemm_bf16<2><<<dim3(4096 / 128, NROWS / 128, 1), 256, 0, stream>>>(
        hbufb, wAt, nullptr, (float*)xb, zb, NROWS, 1024, 2048, 4096);

    // 3. conv + silu -> bf16 u
    conv_silu_kernel<<<(NROWS * D_INNER) / 1024, 256, 0, stream>>>(xb, conv_w, conv_b, ub);

    // 4. xp partials = u @ x_proj_w (split-K = 16, f16 partials)
    gemm_bf16<3><<<dim3(1, NROWS / 128, 16), 256, 0, stream>>>(
        ub, wXt, nullptr, nullptr, xpart16, NROWS, 2048, XPN, XPN);

    // 5. reduce partials -> xp f32 + dt_r bf16
    reduce_xp<<<(NROWS * XPN) / 256, 256, 0, stream>>>(xpart16, xpbuf, dtrb);

    // 6. delta = softplus(dt_r @ dt_proj_w + b) -> bf16 (MFMA)
    gemm_bf16<4><<<dim3(D_INNER / 128, NROWS / 128, 1), 256, 0, stream>>>(
        dtrb, wDt, dt_proj_b, nullptr, deltab, NROWS, 64, D_INNER, D_INNER);

    // 7-9. chunked selective scan + fused gate -> bf16 y
    scan_local<<<NB * NC * (D_INNER / 256), 256, 0, stream>>>(
        xpbuf, deltab, ub, A_log, hst, sdelbuf);
    scan_combine<<<256, 256, 0, stream>>>(A_log, sdelbuf, hst);
    scan_final<<<NB * NC * (D_INNER / 256), 256, 0, stream>>>(
        xpbuf, deltab, ub, zb, hst, A_log, D_param, yb);

    // 10. out partials = y @ out_proj_w (split-K = 4, f16 partials)
    gemm_bf16<3><<<dim3(1024 / 128, NROWS / 128, 4), 256, 0, stream>>>(
        yb, wOt, nullptr, nullptr, opart, NROWS, 2048, 1024, 1024);

    // 11. reduce f16 partials -> d_out
    reduce_out<<<(NROWS * D_MODEL / 4) / 256, 256, 0, stream>>>(opart, out);
}

// Round 12
// 166.638 us; speedup vs baseline: 1.2037x; 1.0013x over previous
//
#include <hip/hip_runtime.h>
#include <hip/hip_bf16.h>

#define D_MODEL 1024
#define D_INNER 2048
#define D_STATE 16
#define DT_RANK 64
#define NB 2
#define LSEQ 1024
#define NROWS (NB * LSEQ)
#define XPN 96
#define NC 32
#define CL 32

typedef __attribute__((ext_vector_type(8))) short bf16x8;
typedef __attribute__((ext_vector_type(8))) unsigned short u16x8;
typedef __attribute__((ext_vector_type(4))) float f32x4;

__device__ __forceinline__ unsigned short f2bf(float x) {
    __hip_bfloat16 h = __float2bfloat16(x);
    return *reinterpret_cast<unsigned short*>(&h);
}
__device__ __forceinline__ float bf2f(unsigned short u) {
    unsigned int v = ((unsigned int)u) << 16;
    float f;
    __builtin_memcpy(&f, &v, 4);
    return f;
}
__device__ __forceinline__ unsigned short f2h(float x) {
    _Float16 h = (_Float16)x;
    unsigned short u;
    __builtin_memcpy(&u, &h, 2);
    return u;
}
__device__ __forceinline__ float h2f(unsigned short u) {
    _Float16 h;
    __builtin_memcpy(&h, &u, 2);
    return (float)h;
}

// ---------------- weight casts + LayerNorm in ONE dispatch ----------------
__global__ __launch_bounds__(256) void wcast_ln(const float* __restrict__ W0, unsigned short* __restrict__ D0,
                                                const float* __restrict__ W1, unsigned short* __restrict__ D1,
                                                const float* __restrict__ W2, unsigned short* __restrict__ D2,
                                                const float* __restrict__ W3, unsigned short* __restrict__ D3,
                                                const float* __restrict__ hx, const float* __restrict__ nw,
                                                const float* __restrict__ nb, unsigned short* __restrict__ lnout) {
    int bid = blockIdx.x;
    if (bid >= 6528) {
        int row = bid - 6528;
        const float4* xr = (const float4*)(hx + (size_t)row * D_MODEL);
        float4 v = xr[threadIdx.x];
        float s = v.x + v.y + v.z + v.w;
        float sq = v.x * v.x + v.y * v.y + v.z * v.z + v.w * v.w;
#pragma unroll
        for (int off = 32; off > 0; off >>= 1) {
            s += __shfl_down(s, off);
            sq += __shfl_down(sq, off);
        }
        __shared__ float ws[4], wq[4];
        __shared__ float smu, srstd;
        int wave = threadIdx.x >> 6;
        if ((threadIdx.x & 63) == 0) { ws[wave] = s; wq[wave] = sq; }
        __syncthreads();
        if (threadIdx.x == 0) {
            float ts = ws[0] + ws[1] + ws[2] + ws[3];
            float tq = wq[0] + wq[1] + wq[2] + wq[3];
            float mu = ts * (1.f / D_MODEL);
            float var = tq * (1.f / D_MODEL) - mu * mu;
            smu = mu;
            srstd = rsqrtf(var + 1e-5f);
        }
        __syncthreads();
        float mu = smu, rstd = srstd;
        float4 wv = ((const float4*)nw)[threadIdx.x];
        float4 bv = ((const float4*)nb)[threadIdx.x];
        ushort4 pk;
        pk.x = f2bf((v.x - mu) * rstd * wv.x + bv.x);
        pk.y = f2bf((v.y - mu) * rstd * wv.y + bv.y);
        pk.z = f2bf((v.z - mu) * rstd * wv.z + bv.z);
        pk.w = f2bf((v.w - mu) * rstd * wv.w + bv.w);
        *(ushort4*)(lnout + (size_t)row * D_MODEL + threadIdx.x * 4) = pk;
        return;
    }
    const float* W;
    unsigned short* Dst;
    int K, Nreal, bx, by;
    if (bid < 4096) { W = W0; Dst = D0; K = 1024; Nreal = 4096; bx = bid & 127; by = bid >> 7; }
    else if (bid < 4352) { int j = bid - 4096; W = W1; Dst = D1; K = 2048; Nreal = 96; bx = j & 3; by = j >> 2; }
    else if (bid < 6400) { int j = bid - 4352; W = W2; Dst = D2; K = 2048; Nreal = 1024; bx = j & 31; by = j >> 5; }
    else { int j = bid - 6400; W = W3; Dst = D3; K = 64; Nreal = 2048; bx = j & 63; by = j >> 6; }
    __shared__ float t[32][33];
    int tn = bx * 32, tk = by * 32;
    for (int e = threadIdx.x; e < 1024; e += 256) {
        int r = e >> 5, c = e & 31;
        int n = tn + c;
        t[r][c] = (n < Nreal) ? W[(size_t)(tk + r) * Nreal + n] : 0.f;
    }
    __syncthreads();
    for (int e = threadIdx.x; e < 1024; e += 256) {
        int r = e >> 5, c = e & 31;
        Dst[(size_t)(tn + r) * K + tk + c] = f2bf(t[c][r]);
    }
}

// ---------------- bf16 MFMA GEMM: C = A[M][K] @ Bt[N][K]^T ----------------
// 128x128 tile, BK=64, T2 source-pre-swizzle; plain raster block order
// (XCD swizzle removed: working sets are L3-resident, swizzle costs ~2% there).
// EPI 0: f32 C (+split-K zoff). EPI 2: xz-split bf16. EPI 3: f16 partials (+zoff, Nreal guard).
// EPI 4: softplus(v+bias[col]) -> bf16 C2.
template <int EPI>
__global__ __launch_bounds__(256) void gemm_bf16(const unsigned short* __restrict__ A,
                                                 const unsigned short* __restrict__ Bt,
                                                 const float* __restrict__ bias,
                                                 float* __restrict__ C,
                                                 void* __restrict__ C2,
                                                 int M, int K, int ldc, int Nreal) {
    __shared__ unsigned short As[128 * 64];
    __shared__ unsigned short Bs[128 * 64];
    int bx = blockIdx.x, by = blockIdx.y;

    int tid = threadIdx.x;
    int lane = tid & 63;
    int wave = tid >> 6;
    int wr = (wave >> 1) * 64, wc = (wave & 1) * 64;
    int bm = by * 128, bn = bx * 128;
    int kchunk = K / gridDim.z;
    int kbeg = blockIdx.z * kchunk;

    f32x4 acc[4][4];
#pragma unroll
    for (int i = 0; i < 4; ++i)
#pragma unroll
        for (int j = 0; j < 4; ++j) acc[i][j] = (f32x4){0.f, 0.f, 0.f, 0.f};

    int ar = lane & 15;
    int kq = lane >> 4;

    for (int k0 = kbeg; k0 < kbeg + kchunk; k0 += 64) {
        __syncthreads();
#pragma unroll
        for (int s = 0; s < 4; ++s) {
            int seg = s * 256 + tid;
            int row = seg >> 3, p = seg & 7;
            int c = p ^ (row & 7);
            __builtin_amdgcn_global_load_lds(
                (const __attribute__((address_space(1))) void*)(A + (size_t)(bm + row) * K + k0 + c * 8),
                (__attribute__((address_space(3))) void*)(As + seg * 8), 16, 0, 0);
        }
#pragma unroll
        for (int s = 0; s < 4; ++s) {
            int seg = s * 256 + tid;
            int row = seg >> 3, p = seg & 7;
            int c = p ^ (row & 7);
            __builtin_amdgcn_global_load_lds(
                (const __attribute__((address_space(1))) void*)(Bt + (size_t)(bn + row) * K + k0 + c * 8),
                (__attribute__((address_space(3))) void*)(Bs + seg * 8), 16, 0, 0);
        }
        __syncthreads();
#pragma unroll
        for (int kk = 0; kk < 2; ++kk) {
            bf16x8 af[4], bfr[4];
#pragma unroll
            for (int i = 0; i < 4; ++i) {
                int row = wr + i * 16 + ar;
                int pos = ((kk << 2) | kq) ^ (row & 7);
                af[i] = *(const bf16x8*)&As[(size_t)row * 64 + pos * 8];
            }
#pragma unroll
            for (int j = 0; j < 4; ++j) {
                int row = wc + j * 16 + ar;
                int pos = ((kk << 2) | kq) ^ (row & 7);
                bfr[j] = *(const bf16x8*)&Bs[(size_t)row * 64 + pos * 8];
            }
#pragma unroll
            for (int i = 0; i < 4; ++i)
#pragma unroll
                for (int j = 0; j < 4; ++j)
                    acc[i][j] = __builtin_amdgcn_mfma_f32_16x16x32_bf16(af[i], bfr[j], acc[i][j], 0, 0, 0);
        }
    }

    int crow0 = bm + wr + (lane >> 4) * 4;
    int ccol0 = bn + wc + (lane & 15);
    size_t zoff = (size_t)blockIdx.z * (size_t)M * ldc;
#pragma unroll
    for (int i = 0; i < 4; ++i)
#pragma unroll
        for (int j = 0; j < 4; ++j) {
            int col = ccol0 + j * 16;
            if (EPI == 0) {
                if (col < Nreal) {
                    float* cp = C + zoff + (size_t)(crow0 + i * 16) * ldc + col;
#pragma unroll
                    for (int rr = 0; rr < 4; ++rr) cp[(size_t)rr * ldc] = acc[i][j][rr];
                }
            } else if (EPI == 2) {
                unsigned short* cx = (unsigned short*)C;
                unsigned short* cz = (unsigned short*)C2;
                if (col < 2048) {
#pragma unroll
                    for (int rr = 0; rr < 4; ++rr)
                        cx[(size_t)(crow0 + i * 16 + rr) * 2048 + col] = f2bf(acc[i][j][rr]);
                } else {
#pragma unroll
                    for (int rr = 0; rr < 4; ++rr)
                        cz[(size_t)(crow0 + i * 16 + rr) * 2048 + (col - 2048)] = f2bf(acc[i][j][rr]);
                }
            } else if (EPI == 3) {
                if (col < Nreal) {
                    unsigned short* cp = (unsigned short*)C2 + zoff + (size_t)(crow0 + i * 16) * ldc + col;
#pragma unroll
                    for (int rr = 0; rr < 4; ++rr) cp[(size_t)rr * ldc] = f2h(acc[i][j][rr]);
                }
            } else {  // EPI == 4
                float bv = bias[col];
                unsigned short* cp = (unsigned short*)C2 + (size_t)(crow0 + i * 16) * ldc + col;
#pragma unroll
                for (int rr = 0; rr < 4; ++rr) {
                    float v = acc[i][j][rr] + bv;
                    v = (v > 20.f) ? v : log1pf(__expf(v));
                    cp[(size_t)rr * ldc] = f2bf(v);
                }
            }
        }
}

// ---------------- split-K reduce for xp (KS=16, f16 partials) ----------------
// col < 64 -> dt_r bf16 only; col >= 64 -> xp f32 only (B/C slice is all scan reads).
__global__ __launch_bounds__(256) void reduce_xp(const unsigned short* __restrict__ part,
                                                 float* __restrict__ xp,
                                                 unsigned short* __restrict__ dtr) {
    int t = blockIdx.x * 256 + threadIdx.x;
    float s = 0.f;
#pragma unroll
    for (int k = 0; k < 16; ++k) s += h2f(part[(size_t)k * ((size_t)NROWS * XPN) + t]);
    int row = t / 96, col = t - row * 96;
    if (col < 64) dtr[(size_t)row * 64 + col] = f2bf(s);
    else xp[t] = s;
}

// ---------------- split-K reduce for out (KS=4, f16 partials) ----------------
__global__ __launch_bounds__(256) void reduce_out(const unsigned short* __restrict__ part,
                                                  float* __restrict__ out) {
    int t = blockIdx.x * 256 + threadIdx.x;
    const size_t stride = (size_t)NROWS * D_MODEL;
    ushort4 p0 = ((const ushort4*)part)[t];
    ushort4 p1 = ((const ushort4*)(part + stride))[t];
    ushort4 p2 = ((const ushort4*)(part + 2 * stride))[t];
    ushort4 p3 = ((const ushort4*)(part + 3 * stride))[t];
    float4 o;
    o.x = h2f(p0.x) + h2f(p1.x) + h2f(p2.x) + h2f(p3.x);
    o.y = h2f(p0.y) + h2f(p1.y) + h2f(p2.y) + h2f(p3.y);
    o.z = h2f(p0.z) + h2f(p1.z) + h2f(p2.z) + h2f(p3.z);
    o.w = h2f(p0.w) + h2f(p1.w) + h2f(p2.w) + h2f(p3.w);
    ((float4*)out)[t] = o;
}

// ---------------- causal depthwise conv (k=4) + SiLU, 8 channels/thread ----------------
__global__ __launch_bounds__(256) void conv_silu_kernel(const unsigned short* __restrict__ xx,
                                                        const float* __restrict__ cw,
                                                        const float* __restrict__ cb,
                                                        unsigned short* __restrict__ outb) {
    int gid = blockIdx.x * 256 + threadIdx.x;
    int d8 = (gid & 255) << 3;
    int bl = gid >> 8;
    int l = bl & (LSEQ - 1);
    const unsigned short* base = xx + (size_t)bl * D_INNER + d8;
    u16x8 zr = {0, 0, 0, 0, 0, 0, 0, 0};
    u16x8 X0 = *(const u16x8*)base;
    u16x8 X1 = (l >= 1) ? *(const u16x8*)(base - D_INNER) : zr;
    u16x8 X2 = (l >= 2) ? *(const u16x8*)(base - 2 * D_INNER) : zr;
    u16x8 X3 = (l >= 3) ? *(const u16x8*)(base - 3 * D_INNER) : zr;
    u16x8 ob;
#pragma unroll
    for (int e = 0; e < 8; ++e) {
        float4 we = *(const float4*)(cw + (size_t)(d8 + e) * 4);
        float acc = cb[d8 + e];
        acc = fmaf(we.w, bf2f(X0[e]), acc);
        acc = fmaf(we.z, bf2f(X1[e]), acc);
        acc = fmaf(we.y, bf2f(X2[e]), acc);
        acc = fmaf(we.x, bf2f(X3[e]), acc);
        ob[e] = f2bf(acc / (1.f + __expf(-acc)));
    }
    *(u16x8*)(outb + (size_t)bl * D_INNER + d8) = ob;
}

// ---------------- scan phase 1: per-chunk local scan (h0 = 0) ----------------
__global__ __launch_bounds__(256) void scan_local(const float* __restrict__ xp,
                                                  const unsigned short* __restrict__ delta,
                                                  const unsigned short* __restrict__ ub,
                                                  const float* __restrict__ A_log,
                                                  float* __restrict__ hst,
                                                  float* __restrict__ sdel) {
    int bc = blockIdx.x >> 3;
    int b = bc >> 5, c = bc & (NC - 1);
    int d = (blockIdx.x & 7) * 256 + threadIdx.x;
    int base_r = b * LSEQ + c * CL;
    __shared__ float Bsm[CL * 16];
    for (int e = threadIdx.x; e < CL * 4; e += 256) {
        int l = e >> 2, q4 = e & 3;
        float4 v = *(const float4*)&xp[(size_t)(base_r + l) * XPN + DT_RANK + q4 * 4];
        *(float4*)&Bsm[l * 16 + q4 * 4] = v;
    }
    __syncthreads();
    float Av[16];
    const float4* ap = (const float4*)(A_log + (size_t)d * 16);
#pragma unroll
    for (int qq = 0; qq < 4; ++qq) {
        float4 a = ap[qq];
        Av[4 * qq + 0] = -__expf(a.x); Av[4 * qq + 1] = -__expf(a.y);
        Av[4 * qq + 2] = -__expf(a.z); Av[4 * qq + 3] = -__expf(a.w);
    }
    float h[16] = {};
    float sd = 0.f;
    const unsigned short* dp = delta + (size_t)base_r * D_INNER + d;
    const unsigned short* up = ub + (size_t)base_r * D_INNER + d;
#pragma unroll 4
    for (int l = 0; l < CL; ++l) {
        float dv = bf2f(dp[(size_t)l * D_INNER]);
        float u = bf2f(up[(size_t)l * D_INNER]);
        float du = dv * u;
        sd += dv;
#pragma unroll
        for (int n = 0; n < 16; ++n) {
            float dA = __expf(dv * Av[n]);
            h[n] = fmaf(dA, h[n], du * Bsm[l * 16 + n]);
        }
    }
    size_t hi = ((size_t)(c * NB + b) * D_INNER + d) * 16;
#pragma unroll
    for (int qq = 0; qq < 4; ++qq) {
        float4 v = make_float4(h[4 * qq], h[4 * qq + 1], h[4 * qq + 2], h[4 * qq + 3]);
        *(float4*)(hst + hi + 4 * qq) = v;
    }
    sdel[(size_t)(c * NB + b) * D_INNER + d] = sd;
}

// ---------------- scan phase 2: cross-chunk combine (LDS-staged walk) ----------------
__global__ __launch_bounds__(256) void scan_combine(const float* __restrict__ A_log,
                                                    const float* __restrict__ sdel,
                                                    float* __restrict__ hst) {
    __shared__ float hl[NC][256];
    __shared__ float sl[NC][16];
    int b = blockIdx.x >> 7;
    int d0 = (blockIdx.x & 127) * 16;
    int t = threadIdx.x;
    int dd = t >> 4;
    for (int e = t; e < NC * 256; e += 256) {
        int c = e >> 8, tt = e & 255;
        hl[c][tt] = hst[(size_t)(c * NB + b) * (D_INNER * 16) + d0 * 16 + tt];
    }
    for (int e = t; e < NC * 16; e += 256) {
        int c = e >> 4, ddd = e & 15;
        sl[c][ddd] = sdel[(size_t)(c * NB + b) * D_INNER + d0 + ddd];
    }
    __syncthreads();
    float Avn = -__expf(A_log[(size_t)d0 * 16 + t]);
    float h = 0.f;
#pragma unroll
    for (int c = 0; c < NC; ++c) {
        float S = sl[c][dd];
        float tmp = hl[c][t];
        hl[c][t] = h;
        h = fmaf(__expf(Avn * S), h, tmp);
    }
    __syncthreads();
    for (int e = t; e < NC * 256; e += 256) {
        int c = e >> 8, tt = e & 255;
        hst[(size_t)(c * NB + b) * (D_INNER * 16) + d0 * 16 + tt] = hl[c][tt];
    }
}

// ---------------- scan phase 3: finalize, fuse silu(z) gate -> bf16 y ----------------
__global__ __launch_bounds__(256) void scan_final(const float* __restrict__ xp,
                                                  const unsigned short* __restrict__ delta,
                                                  const unsigned short* __restrict__ ub,
                                                  const unsigned short* __restrict__ zb,
                                                  const float* __restrict__ hst,
                                                  const float* __restrict__ A_log,
                                                  const float* __restrict__ Dp,
                                                  unsigned short* __restrict__ yb) {
    int bc = blockIdx.x >> 3;
    int b = bc >> 5, c = bc & (NC - 1);
    int d = (blockIdx.x & 7) * 256 + threadIdx.x;
    int base_r = b * LSEQ + c * CL;
    __shared__ float Bsm[CL * 16], Csm[CL * 16];
    for (int e = threadIdx.x; e < CL * 8; e += 256) {
        int l = e >> 3, q8 = e & 7;
        float4 v = *(const float4*)&xp[(size_t)(base_r + l) * XPN + DT_RANK + q8 * 4];
        if (q8 < 4) *(float4*)&Bsm[l * 16 + q8 * 4] = v;
        else *(float4*)&Csm[l * 16 + (q8 - 4) * 4] = v;
    }
    __syncthreads();
    float Av[16];
    const float4* ap = (const float4*)(A_log + (size_t)d * 16);
#pragma unroll
    for (int qq = 0; qq < 4; ++qq) {
        float4 a = ap[qq];
        Av[4 * qq + 0] = -__expf(a.x); Av[4 * qq + 1] = -__expf(a.y);
        Av[4 * qq + 2] = -__expf(a.z); Av[4 * qq + 3] = -__expf(a.w);
    }
    float h[16];
    size_t hi = ((size_t)(c * NB + b) * D_INNER + d) * 16;
#pragma unroll
    for (int qq = 0; qq < 4; ++qq) {
        float4 v = *(const float4*)(hst + hi + 4 * qq);
        h[4 * qq] = v.x; h[4 * qq + 1] = v.y; h[4 * qq + 2] = v.z; h[4 * qq + 3] = v.w;
    }
    float Dv = Dp[d];
    const unsigned short* dp = delta + (size_t)base_r * D_INNER + d;
    const unsigned short* up = ub + (size_t)base_r * D_INNER + d;
    const unsigned short* zp = zb + (size_t)base_r * D_INNER + d;
#pragma unroll 4
    for (int l = 0; l < CL; ++l) {
        float dv = bf2f(dp[(size_t)l * D_INNER]);
        float u = bf2f(up[(size_t)l * D_INNER]);
        float du = dv * u;
        float acc = 0.f;
#pragma unroll
        for (int n = 0; n < 16; ++n) {
            float dA = __expf(dv * Av[n]);
            h[n] = fmaf(dA, h[n], du * Bsm[l * 16 + n]);
            acc = fmaf(h[n], Csm[l * 16 + n], acc);
        }
        float yv = fmaf(u, Dv, acc);
        float zv = bf2f(zp[(size_t)l * D_INNER]);
        float sz = zv / (1.f + __expf(-zv));
        yb[(size_t)(base_r + l) * D_INNER + d] = f2bf(yv * sz);
    }
}

extern "C" void kernel_launch(void* const* d_in, const int* in_sizes, int n_in,
                              void* d_out, int out_size, void* d_ws, size_t ws_size,
                              hipStream_t stream) {
    const float* hidden = (const float*)d_in[0];
    const float* norm_w = (const float*)d_in[1];
    const float* norm_b = (const float*)d_in[2];
    const float* in_proj_w = (const float*)d_in[3];
    const float* conv_w = (const float*)d_in[4];
    const float* conv_b = (const float*)d_in[5];
    const float* x_proj_w = (const float*)d_in[6];
    const float* dt_proj_w = (const float*)d_in[7];
    const float* dt_proj_b = (const float*)d_in[8];
    const float* A_log = (const float*)d_in[9];
    const float* D_param = (const float*)d_in[10];
    const float* out_proj_w = (const float*)d_in[11];
    float* out = (float*)d_out;

    float* wsf = (float*)d_ws;
    unsigned short* hbufb = (unsigned short*)wsf;
    float* xpbuf = wsf;
    float* sdelbuf = wsf + 196608;
    unsigned short* xb = (unsigned short*)(wsf + 1048576);
    float* hst = wsf + 1048576;
    unsigned short* zb = (unsigned short*)(wsf + 3145728);
    unsigned short* ub = (unsigned short*)(wsf + 5242880);
    unsigned short* yb = ub;
    unsigned short* wAt = (unsigned short*)(wsf + 7340032);
    unsigned short* xpart16 = (unsigned short*)(wsf + 7340032);
    unsigned short* opart = (unsigned short*)(wsf + 7340032);
    unsigned short* wXt = (unsigned short*)(wsf + 10485760);
    unsigned short* wDt = (unsigned short*)(wsf + 10616832);
    unsigned short* dtrb = (unsigned short*)(wsf + 10682368);
    unsigned short* deltab = (unsigned short*)(wsf + 11665408);
    unsigned short* wOt = (unsigned short*)(wsf + 13762560);

    // 1. all weight casts + LayerNorm, one dispatch
    wcast_ln<<<6528 + NROWS, 256, 0, stream>>>(in_proj_w, wAt, x_proj_w, wXt, out_proj_w, wOt,
                                               dt_proj_w, wDt, hidden, norm_w, norm_b, hbufb);

    // 2. xz = h @ in_proj_w : x-half bf16 -> xb, z-half bf16 -> zb
    gemm_bf16<2><<<dim3(4096 / 128, NROWS / 128, 1), 256, 0, stream>>>(
        hbufb, wAt, nullptr, (float*)xb, zb, NROWS, 1024, 2048, 4096);

    // 3. conv + silu -> bf16 u (8 ch/thread)
    conv_silu_kernel<<<(NROWS * D_INNER) / 2048, 256, 0, stream>>>(xb, conv_w, conv_b, ub);

    // 4. xp partials = u @ x_proj_w (split-K = 16, f16 partials)
    gemm_bf16<3><<<dim3(1, NROWS / 128, 16), 256, 0, stream>>>(
        ub, wXt, nullptr, nullptr, xpart16, NROWS, 2048, XPN, XPN);

    // 5. reduce partials -> xp f32 (cols>=64) + dt_r bf16 (cols<64)
    reduce_xp<<<(NROWS * XPN) / 256, 256, 0, stream>>>(xpart16, xpbuf, dtrb);

    // 6. delta = softplus(dt_r @ dt_proj_w + b) -> bf16 (MFMA)
    gemm_bf16<4><<<dim3(D_INNER / 128, NROWS / 128, 1), 256, 0, stream>>>(
        dtrb, wDt, dt_proj_b, nullptr, deltab, NROWS, 64, D_INNER, D_INNER);

    // 7-9. chunked selective scan + fused gate -> bf16 y
    scan_local<<<NB * NC * (D_INNER / 256), 256, 0, stream>>>(
        xpbuf, deltab, ub, A_log, hst, sdelbuf);
    scan_combine<<<256, 256, 0, stream>>>(A_log, sdelbuf, hst);
    scan_final<<<NB * NC * (D_INNER / 256), 256, 0, stream>>>(
        xpbuf, deltab, ub, zb, hst, A_log, D_param, yb);

    // 10. out partials = y @ out_proj_w (split-K = 4, f16 partials)
    gemm_bf16<3><<<dim3(1024 / 128, NROWS / 128, 4), 256, 0, stream>>>(
        yb, wOt, nullptr, nullptr, opart, NROWS, 2048, 1024, 1024);

    // 11. reduce f16 partials -> d_out
    reduce_out<<<(NROWS * D_MODEL / 4) / 256, 256, 0, stream>>>(opart, out);
}